// Round 6
// baseline (620.506 us; speedup 1.0000x reference)
//
#include <hip/hip_runtime.h>
#include <hip/hip_bf16.h>

// ---------------------------------------------------------------------------
// HybridGATLSTM on MI355X — round 12.
//   r11 post-mortem: fused kernel is LSTM-bound (290us = LSTM; GAT hides).
//   Step cost ~2400cyc = 2x wave-issue(~573) + ~1100 fixed latency.
//   Round 12 cuts both terms with EXACT fp32 math (absmax must not move):
//     (1) recurrence dot via inline-asm v_pk_fma_f32 (packed dual fp32 FMA;
//         compiler provably wasn't packing: VALUBusy matched scalar model).
//         Dot issue 256 -> 128 cyc/wave/step.
//     (2) Pre staged in LDS, 32-step chunks per layer (proj MFMA stores its
//         slice straight to LDS; rec reads it as broadcast ds_reads). Kills
//         the per-step L2/HBM Pre exposure (GAT streaming was evicting it).
//         Hseq moves to global ping-pong buffers (A->B->A: a buffer's lines
//         are never in L1 before first read -> no stale-L1 hazard).
//   LDS union: Pre[32][516] + hbuf = 70.4KB -> still 2 blocks/CU.
//   GAT body, heads, launch structure: r11 verbatim (verified).
// ---------------------------------------------------------------------------

typedef _Float16 half8 __attribute__((ext_vector_type(8)));
typedef float floatx4 __attribute__((ext_vector_type(4)));
typedef float float4v __attribute__((ext_vector_type(4)));
typedef float float2v __attribute__((ext_vector_type(2)));

#define LOG2E 1.44269504088896f

__device__ __forceinline__ float fast_exp(float x) {
    return __builtin_amdgcn_exp2f(x * LOG2E);
}
__device__ __forceinline__ float sigm(float x) {
    x = fminf(fmaxf(x, -30.f), 30.f);
    return __builtin_amdgcn_rcpf(1.f + __builtin_amdgcn_exp2f(-x * LOG2E));
}
__device__ __forceinline__ float tanhp(float x) {
    x = fminf(fmaxf(x, -15.f), 15.f);
    float e = __builtin_amdgcn_exp2f(-2.f * LOG2E * x);
    return (1.f - e) * __builtin_amdgcn_rcpf(1.f + e);
}
__device__ __forceinline__ void split8v(float4v v0, float4v v1, half8& hi, half8& lo) {
#pragma unroll
    for (int j = 0; j < 4; ++j) {
        _Float16 h = (_Float16)v0[j];
        hi[j] = h; lo[j] = (_Float16)(v0[j] - (float)h);
    }
#pragma unroll
    for (int j = 0; j < 4; ++j) {
        _Float16 h = (_Float16)v1[j];
        hi[4 + j] = h; lo[4 + j] = (_Float16)(v1[j] - (float)h);
    }
}

// packed dual-fp32 FMA: p.xy += w.xy * h.xy  (exact fp32, 1 instr / 2 MACs)
#define PKFMA(p, w, h) \
    asm("v_pk_fma_f32 %0, %1, %2, %0" : "+v"(p) : "v"(w), "v"(h))

// ---------------------------------------------------------------------------
// Shared-memory layouts (union'd).
// LstmSh: Pre chunk [32 steps][512+4 pad] (66.0KB) + hbuf (4.3KB) = 70.4KB.
// GatSh ~44.5KB. Union 70.4KB -> 2 blocks/CU (140.8KB <= 160KB).
// ---------------------------------------------------------------------------
struct LstmSh {
    float Pre[32 * 516];    // current 32-step Pre slice (padded rows: 516)
    float hbuf[2][544];     // 2 buffers x 4 bank-shifted copies(136)
};
struct GatSh {
    unsigned long long adjm[256];   // adj bitmask: row i -> adjm[2i],adjm[2i+1]
    float xv[128];
    float u1[32], v1[32], coef[4];
    float s1v[128];
    float h2s[128 * 33];
    float wh2[128 * 17];
    float Lv[128], Rv[128], rd2[128];
    float d_h[4][128], s_h[4][128];
};
union ShU { LstmSh l; GatSh g; };

// ---------------------------------------------------------------------------
// LSTM body: one block per batch element, 512 threads.
// Per layer, 3 chunks of 32 steps: [proj (2 mt-tiles) -> LDS Pre] then
// [rec 32 steps: pk_fma dot, shfl butterfly, 1 barrier/step].
// Hseq: global ping-pong (prev = input seq of this layer, cur = output).
// ---------------------------------------------------------------------------
__device__ __forceinline__ void lstm_body(LstmSh& sh, int b,
    const float* __restrict__ x,     // [16][96][128]
    const float* __restrict__ Wih,   // [3][512][128]
    const float* __restrict__ Whh,   // [3][512][128]
    const float* __restrict__ bih,   // [3][512]
    const float* __restrict__ bhh,   // [3][512]
    float* __restrict__ HseqA,       // this block: 96*128 floats
    float* __restrict__ HseqB,       // this block: 96*128 floats
    float* __restrict__ xl_out)      // [16][128]
{
    int tid = threadIdx.x;
    int w = tid >> 6, lane = tid & 63, quad = lane >> 4, sub = lane & 15;

    // rec decomposition: hu = 16w + sub, K-chunk c = quad (32 K each)
    int hu = 16 * w + sub;
    int c4 = quad;

    __builtin_amdgcn_s_setprio(1);   // LSTM is the critical path when fused

    for (int layer = 0; layer < 3; ++layer) {
        const float* WihL = Wih + layer * 65536;
        const float* WhhL = Whh + layer * 65536;
        // ping-pong: layer0 reads x, writes A; layer1 reads A writes B;
        // layer2 reads B (writes only xl).
        const float* HseqPrev = (layer == 1) ? HseqA : HseqB;
        float* HseqCur = (layer == 0) ? HseqA : HseqB;

        // zero h-state (all 4 copies of buffer 0) + cell state
        sh.hbuf[0][c4 * 136 + hu] = 0.f;
        float cvar = 0.f;

        for (int chunk = 0; chunk < 3; ++chunk) {
            // ======== proj phase: Pre_lds[mloc][r] = A[t].Wih[r]+bias,
            //          mt in {2*chunk, 2*chunk+1} (32 timesteps)
            {
                half8 bhi[4][4], blo[4][4];
                float bias[4];
#pragma unroll
                for (int tt = 0; tt < 4; ++tt) {
                    int r = tt * 128 + 16 * w + sub;
                    bias[tt] = bih[layer * 512 + r] + bhh[layer * 512 + r];
#pragma unroll
                    for (int kc = 0; kc < 4; ++kc) {
                        const float4v* p = (const float4v*)(WihL + r * 128 + kc * 32 + quad * 8);
                        split8v(p[0], p[1], bhi[tt][kc], blo[tt][kc]);
                    }
                }
                for (int mtl = 0; mtl < 2; ++mtl) {
                    int mt = chunk * 2 + mtl;
                    half8 ahi[4], alo[4];
                    const float* arow = (layer == 0)
                        ? (x + b * 12288 + (mt * 16 + sub) * 128)
                        : (HseqPrev + (mt * 16 + sub) * 128);
#pragma unroll
                    for (int kc = 0; kc < 4; ++kc) {
                        const float4v* p = (const float4v*)(arow + kc * 32 + quad * 8);
                        split8v(p[0], p[1], ahi[kc], alo[kc]);
                    }
                    floatx4 acc[4];
#pragma unroll
                    for (int tt = 0; tt < 4; ++tt) {
                        floatx4 a = {bias[tt], bias[tt], bias[tt], bias[tt]};
                        acc[tt] = a;
                    }
#pragma unroll
                    for (int tt = 0; tt < 4; ++tt)
#pragma unroll
                        for (int kc = 0; kc < 4; ++kc) {
                            acc[tt] = __builtin_amdgcn_mfma_f32_16x16x32_f16(ahi[kc], bhi[tt][kc], acc[tt], 0, 0, 0);
                            acc[tt] = __builtin_amdgcn_mfma_f32_16x16x32_f16(ahi[kc], blo[tt][kc], acc[tt], 0, 0, 0);
                            acc[tt] = __builtin_amdgcn_mfma_f32_16x16x32_f16(alo[kc], bhi[tt][kc], acc[tt], 0, 0, 0);
                        }
                    // local step mloc = mtl*16 + quad*4 + reg, row = tt*128+16w+sub
                    // bank pattern: 516%32=4 -> 2-way max (free)
#pragma unroll
                    for (int tt = 0; tt < 4; ++tt)
#pragma unroll
                        for (int reg = 0; reg < 4; ++reg)
                            sh.Pre[(mtl * 16 + quad * 4 + reg) * 516 + tt * 128 + 16 * w + sub] = acc[tt][reg];
                }
            }
            __syncthreads();   // Pre slice visible; (chunk0) hbuf zero visible

            // ======== rec phase: 32 steps. Weights reloaded per chunk so
            // their lifetime doesn't overlap proj's bhi/blo (VGPR cliff).
            float2v wgt[4][16];
#pragma unroll
            for (int g = 0; g < 4; ++g) {
                const float2v* wp = (const float2v*)(WhhL + (g * 128 + hu) * 128 + c4 * 32);
#pragma unroll
                for (int k = 0; k < 16; ++k) wgt[g][k] = wp[k];
            }

            for (int tl = 0; tl < 32; ++tl) {
                int t = chunk * 32 + tl;
                int rb = t & 1, wb = rb ^ 1;
                // Pre from LDS: all 4 c-lanes same address -> broadcast, free
                float pre[4];
#pragma unroll
                for (int g = 0; g < 4; ++g)
                    pre[g] = sh.Pre[tl * 516 + g * 128 + hu];

                // h chunk from this lane's bank-shifted copy (base c4*136 +
                // element offset c4*32 = c4*168): conflict-free broadcast
                const float2v* hc2 = (const float2v*)(&sh.hbuf[rb][c4 * 168]);
                float2v hvv[16];
#pragma unroll
                for (int k = 0; k < 16; ++k) hvv[k] = hc2[k];

                float2v p2[4];
#pragma unroll
                for (int g = 0; g < 4; ++g) {
                    float2v z = {0.f, 0.f};
                    p2[g] = z;
                }
#pragma unroll
                for (int k = 0; k < 16; ++k) {
#pragma unroll
                    for (int g = 0; g < 4; ++g)
                        PKFMA(p2[g], wgt[g][k], hvv[k]);
                }
                float p[4];
#pragma unroll
                for (int g = 0; g < 4; ++g) {
                    float s = p2[g].x + p2[g].y;
                    s += __shfl_xor(s, 16, 64);   // combine chunk pairs
                    s += __shfl_xor(s, 32, 64);   // combine halves
                    p[g] = s + pre[g];
                }
                // all 4 c-lanes compute identical activations (coherent cvar)
                float c = sigm(p[1]) * cvar + sigm(p[0]) * tanhp(p[2]);
                cvar = c;
                float h = sigm(p[3]) * tanhp(c);
                sh.hbuf[wb][c4 * 136 + hu] = h;      // each lane updates its copy
                if (c4 == 0) {
                    if (layer < 2) HseqCur[t * 128 + hu] = h;
                    else if (t == 95) xl_out[b * 128 + hu] = h;
                }
                __syncthreads();   // h visible; Pre/hbuf reads complete
            }
        }
    }
    __builtin_amdgcn_s_setprio(0);
}

// ---------------------------------------------------------------------------
// GAT body: r11 VERBATIM. One block per graph (b,s), 512 threads.
// Ballot bitmask + single-pass no-max softmax + fused tile write.
// ---------------------------------------------------------------------------
__device__ __forceinline__ void gat_body(GatSh& s, int m,
    const float* __restrict__ x, const float* __restrict__ adj,
    const float* __restrict__ W_emb, const float* __restrict__ b_emb,
    const float* __restrict__ W1, const float* __restrict__ a1,
    const float* __restrict__ W2, const float* __restrict__ a2,
    float* __restrict__ attn_out, float* __restrict__ xg)
{
    int tid = threadIdx.x;

    // ---- stage: xv, adjacency bitmask (ballot), u1/v1
    if (tid < 128) s.xv[tid] = x[m * 128 + tid];
#pragma unroll
    for (int base = 0; base < 16384; base += 512) {
        int idx = base + tid;
        unsigned long long msk = __ballot(adj[idx] > 0.f);
        if ((tid & 63) == 0) s.adjm[idx >> 6] = msk;
    }
    if (tid < 32) {
        float su = 0.f, sv = 0.f;
        for (int kk = 0; kk < 32; ++kk) {
            float w1v = W1[kk * 32 + tid];
            su += W_emb[kk] * w1v;
            sv += b_emb[kk] * w1v;
        }
        s.u1[tid] = su; s.v1[tid] = sv;
    }
    __syncthreads();
    if (tid < 4) {
        const float* av = a1 + ((tid >= 2) ? 32 : 0);
        const float* uv = (tid & 1) ? s.v1 : s.u1;
        float sum = 0.f;
        for (int f = 0; f < 32; ++f) sum += uv[f] * av[f];
        s.coef[tid] = sum;
    }
    __syncthreads();
    float cL = s.coef[0], dL = s.coef[1], cR = s.coef[2], dR = s.coef[3];

    // ---- GAT1: single-pass den/wsum (no max: |e| bounded for this model)
    {
        int i = tid & 127, q = tid >> 7;   // q in [0,4): 32-wide j slice
        unsigned int ms = (unsigned int)(s.adjm[(i << 1) | (q >> 1)] >> ((q & 1) * 32));
        float Li = s.xv[i] * cL + dL;
        float den = 0.f, wsum = 0.f;
        int j0 = q * 32;
#pragma unroll
        for (int jj = 0; jj < 32; ++jj) {
            if ((ms >> jj) & 1) {
                float xj = s.xv[j0 + jj];
                float e = Li + xj * cR + dR;
                e = e > 0.f ? e : 0.2f * e;
                float p = fast_exp(e);
                den += p; wsum += p * xj;
            }
        }
        s.d_h[q][i] = den; s.s_h[q][i] = wsum;
    }
    __syncthreads();
    if (tid < 128) {
        float den = 0.f, wsum = 0.f;
#pragma unroll
        for (int q = 0; q < 4; ++q) { den += s.d_h[q][tid]; wsum += s.s_h[q][tid]; }
        s.s1v[tid] = wsum / den;
    }
    __syncthreads();
    // ---- h2 = elu(s1*u1 + v1)
#pragma unroll
    for (int e0 = 0; e0 < 4096; e0 += 512) {
        int e = e0 + tid;
        int i = e >> 5, f = e & 31;
        float v = s.s1v[i] * s.u1[f] + s.v1[f];
        s.h2s[i * 33 + f] = v > 0.f ? v : fast_exp(v) - 1.f;
    }
    __syncthreads();
    // ---- Wh2 = h2 @ W2  (128x32 @ 32x16), 4 threads/row
    {
        int i = tid >> 2, g0 = (tid & 3) * 4;
        float accv[4] = {0.f, 0.f, 0.f, 0.f};
        for (int f = 0; f < 32; ++f) {
            float hv = s.h2s[i * 33 + f];
#pragma unroll
            for (int g = 0; g < 4; ++g) accv[g] += hv * W2[f * 16 + g0 + g];
        }
#pragma unroll
        for (int g = 0; g < 4; ++g) s.wh2[i * 17 + g0 + g] = accv[g];
    }
    __syncthreads();
    if (tid < 256) {
        int i = tid & 127, which = tid >> 7;
        const float* aa = a2 + which * 16;
        float sum = 0.f;
#pragma unroll
        for (int g = 0; g < 16; ++g) sum += s.wh2[i * 17 + g] * aa[g];
        (which ? s.Rv : s.Lv)[i] = sum;
    }
    __syncthreads();
    // ---- attn2: single-pass den
    {
        int i = tid & 127, q = tid >> 7;
        unsigned int ms = (unsigned int)(s.adjm[(i << 1) | (q >> 1)] >> ((q & 1) * 32));
        float Li = s.Lv[i];
        float den = 0.f;
        int j0 = q * 32;
#pragma unroll
        for (int jj = 0; jj < 32; ++jj) {
            if ((ms >> jj) & 1) {
                float e = Li + s.Rv[j0 + jj];
                e = e > 0.f ? e : 0.2f * e;
                den += fast_exp(e);
            }
        }
        s.d_h[q][i] = den;
    }
    __syncthreads();
    if (tid < 128) {
        float den = 0.f;
#pragma unroll
        for (int q = 0; q < 4; ++q) den += s.d_h[q][tid];
        s.rd2[tid] = 1.0f / den;
    }
    __syncthreads();

    // ---- full 16384-float tile write (float4), mask from bitmask
    float* aout = attn_out + (size_t)m * 16384;
#pragma unroll
    for (int k = 0; k < 8; ++k) {
        int e0 = k * 2048 + tid * 4;
        int i = e0 >> 7, j0 = e0 & 127;
        unsigned int bits = (unsigned int)(s.adjm[(i << 1) | (j0 >> 6)] >> (j0 & 63)) & 0xFu;
        float Li = s.Lv[i], ri = s.rd2[i];
        float4v p;
#pragma unroll
        for (int u = 0; u < 4; ++u) {
            float pv = 0.f;
            if ((bits >> u) & 1) {
                float e = Li + s.Rv[j0 + u];
                e = e > 0.f ? e : 0.2f * e;
                pv = fast_exp(e) * ri;
            }
            p[u] = pv;
        }
        *(float4v*)(aout + e0) = p;
    }

    // out2 = attn2 @ Wh2 only for the last timestep of each batch -> global XG
    if (m % 96 == 95) {
        int b = m / 96;
        int i = tid >> 2, g0 = (tid & 3) * 4;
        unsigned long long mA = s.adjm[i << 1], mB = s.adjm[(i << 1) | 1];
        float Li = s.Lv[i], ri = s.rd2[i];
        float accv[4] = {0.f, 0.f, 0.f, 0.f};
        for (int j = 0; j < 128; ++j) {
            unsigned long long mm = (j < 64) ? mA : mB;
            if ((mm >> (j & 63)) & 1) {
                float e = Li + s.Rv[j];
                e = e > 0.f ? e : 0.2f * e;
                float p = fast_exp(e) * ri;
#pragma unroll
                for (int g = 0; g < 4; ++g) accv[g] += p * s.wh2[j * 17 + g0 + g];
            }
        }
#pragma unroll
        for (int g = 0; g < 4; ++g) xg[b * 2048 + i * 16 + g0 + g] = accv[g];
    }
}

// ---------------------------------------------------------------------------
// Fused kernel: blocks 0..15 LSTM, 16..1551 GAT.
// ---------------------------------------------------------------------------
__global__ __launch_bounds__(512, 2) void fused_kernel(
    const float* __restrict__ x, const float* __restrict__ adj,
    const float* __restrict__ W_emb, const float* __restrict__ b_emb,
    const float* __restrict__ W1, const float* __restrict__ a1,
    const float* __restrict__ W2, const float* __restrict__ a2,
    const float* __restrict__ Wih, const float* __restrict__ Whh,
    const float* __restrict__ bih, const float* __restrict__ bhh,
    float* __restrict__ HseqA, float* __restrict__ HseqB,
    float* __restrict__ xl_out,
    float* __restrict__ attn_out, float* __restrict__ xg)
{
    __shared__ ShU sh;
    int bb = blockIdx.x;
    if (bb < 16) {
        lstm_body(sh.l, bb, x, Wih, Whh, bih, bhh,
                  HseqA + bb * 12288, HseqB + bb * 12288, xl_out);
    } else {
        gat_body(sh.g, bb - 16, x, adj, W_emb, b_emb, W1, a1, W2, a2, attn_out, xg);
    }
}

// ---------------------------------------------------------------------------
// Heads (r11 verbatim)
// ---------------------------------------------------------------------------
__global__ __launch_bounds__(256) void head_partial_kernel(
    const float* __restrict__ xl, const float* __restrict__ xg,
    const float* __restrict__ W1, float* __restrict__ hp)
{
    int k = blockIdx.x >> 4, chunk = blockIdx.x & 15;
    int d = threadIdx.x & 63, bg = threadIdx.x >> 6;
    float acc[4] = {0.f, 0.f, 0.f, 0.f};
    int c0 = chunk * 136;
    for (int cc = c0; cc < c0 + 136; ++cc) {
        float wv = W1[(k * 2176 + cc) * 64 + d];
#pragma unroll
        for (int u = 0; u < 4; ++u) {
            int b = bg * 4 + u;
            float cv = (cc < 128) ? xl[b * 128 + cc] : xg[b * 2048 + cc - 128];
            acc[u] += wv * cv;
        }
    }
#pragma unroll
    for (int u = 0; u < 4; ++u)
        hp[(((k * 16 + chunk) * 16) + bg * 4 + u) * 64 + d] = acc[u];
}

__global__ __launch_bounds__(256) void head_final_kernel(
    const float* __restrict__ hp, const float* __restrict__ b1,
    const float* __restrict__ W2, const float* __restrict__ b2,
    const float* __restrict__ W3d, const float* __restrict__ b3d,
    const float* __restrict__ W3r, const float* __restrict__ b3r,
    const float* __restrict__ W3v, const float* __restrict__ b3v,
    float* __restrict__ out)
{
    __shared__ float h1s[3 * 16 * 64];
    __shared__ float h2s[3 * 16 * 32];
    int tid = threadIdx.x;
    for (int o = tid; o < 3072; o += 256) {
        int k = o >> 10, rem = o & 1023, b = rem >> 6, d = rem & 63;
        float s = b1[k * 64 + d];
        for (int ch = 0; ch < 16; ++ch)
            s += hp[(((k * 16 + ch) * 16) + b) * 64 + d];
        h1s[o] = fmaxf(s, 0.f);
    }
    __syncthreads();
    for (int o = tid; o < 1536; o += 256) {
        int k = o >> 9, rem = o & 511, b = rem >> 5, e = rem & 31;
        float s = b2[k * 32 + e];
        for (int dd = 0; dd < 64; ++dd)
            s += h1s[(k * 16 + b) * 64 + dd] * W2[(k * 64 + dd) * 32 + e];
        h2s[o] = fmaxf(s, 0.f);
    }
    __syncthreads();
    if (tid < 64) {
        if (tid < 16) {
            int b = tid; float s = b3d[0];
            for (int e = 0; e < 32; ++e) s += h2s[b * 32 + e] * W3d[e];
            out[b] = s;
        } else if (tid < 32) {
            int b = tid - 16; float s = b3r[0];
            for (int e = 0; e < 32; ++e) s += h2s[(16 + b) * 32 + e] * W3r[e];
            out[16 + b] = s;
        } else {
            int b = (tid - 32) >> 1, j = tid & 1; float s = b3v[j];
            for (int e = 0; e < 32; ++e) s += h2s[(32 + b) * 32 + e] * W3v[e * 2 + j];
            out[32 + b * 2 + j] = s;
        }
    }
}

// ---------------------------------------------------------------------------
extern "C" void kernel_launch(void* const* d_in, const int* in_sizes, int n_in,
                              void* d_out, int out_size, void* d_ws, size_t ws_size,
                              hipStream_t stream)
{
    const float* x     = (const float*)d_in[0];
    const float* adj   = (const float*)d_in[1];
    const float* W_emb = (const float*)d_in[2];
    const float* b_emb = (const float*)d_in[3];
    const float* W1    = (const float*)d_in[4];
    const float* a1    = (const float*)d_in[5];
    const float* W2    = (const float*)d_in[6];
    const float* a2    = (const float*)d_in[7];
    const float* Wih   = (const float*)d_in[8];
    const float* Whh   = (const float*)d_in[9];
    const float* bih   = (const float*)d_in[10];
    const float* bhh   = (const float*)d_in[11];
    const float* hW1   = (const float*)d_in[12];
    const float* hb1   = (const float*)d_in[13];
    const float* hW2   = (const float*)d_in[14];
    const float* hb2   = (const float*)d_in[15];
    const float* W3d   = (const float*)d_in[16];
    const float* b3d   = (const float*)d_in[17];
    const float* W3r   = (const float*)d_in[18];
    const float* b3r   = (const float*)d_in[19];
    const float* W3v   = (const float*)d_in[20];
    const float* b3v   = (const float*)d_in[21];

    float* out = (float*)d_out;
    float* wsf = (float*)d_ws;
    float* XG    = wsf;                   // 16*2048
    float* XL    = wsf + 32768;           // 16*128
    float* HP    = wsf + 34816;           // 3*16*16*64
    float* HSEQA = wsf + 83968;           // 16 * 96*128
    float* HSEQB = wsf + 280576;          // 16 * 96*128

    fused_kernel<<<1552, 512, 0, stream>>>(
        x, adj, W_emb, b_emb, W1, a1, W2, a2,
        Wih, Whh, bih, bhh, HSEQA, HSEQB, XL, out + 64, XG);
    head_partial_kernel<<<48, 256, 0, stream>>>(XL, XG, hW1, HP);
    head_final_kernel<<<1, 256, 0, stream>>>(HP, hb1, hW2, hb2, W3d, b3d, W3r, b3r, W3v, b3v, out);
}

// Round 7
// 480.907 us; speedup vs baseline: 1.2903x; 1.2903x over previous
//
#include <hip/hip_runtime.h>
#include <hip/hip_bf16.h>

// ---------------------------------------------------------------------------
// HybridGATLSTM on MI355X — round 13.
//   r12 post-mortem: LDS-Pre chunking caused 9x weight/B-tile refetch per
//   layer (FETCH 12.2->14.9MB) + proj/rec serialization -> fused 290->452.
//   r6 standalone LSTM (warm L2, no contention) was already 275us, so the
//   "Pre L2 exposure" theory was wrong for the base; it only matters for the
//   fused delta (GAT evicts L2).
//   Round 13 = r11 VERBATIM (verified 290us fused) + two bit-exact edits in
//   the recurrence inner loop only:
//     (1) v_pk_fma_f32 on float2-halves of the SAME accumulators, same k
//         order, same final sum order -> bit-identical fp32, half the FMA
//         issue (128 -> 64 instr/step/lane).
//     (2) Pre(t+1) register prefetch: issued at step start, consumed next
//         step -> a full step of latency cover under GAT L2 eviction.
//   absmax must stay exactly 0.0001220703 (bit-exactness canary).
// ---------------------------------------------------------------------------

typedef _Float16 half8 __attribute__((ext_vector_type(8)));
typedef float floatx4 __attribute__((ext_vector_type(4)));
typedef float float4v __attribute__((ext_vector_type(4)));
typedef float float2v __attribute__((ext_vector_type(2)));

#define LOG2E 1.44269504088896f

__device__ __forceinline__ float fast_exp(float x) {
    return __builtin_amdgcn_exp2f(x * LOG2E);
}
__device__ __forceinline__ float sigm(float x) {
    x = fminf(fmaxf(x, -30.f), 30.f);
    return __builtin_amdgcn_rcpf(1.f + __builtin_amdgcn_exp2f(-x * LOG2E));
}
__device__ __forceinline__ float tanhp(float x) {
    x = fminf(fmaxf(x, -15.f), 15.f);
    float e = __builtin_amdgcn_exp2f(-2.f * LOG2E * x);
    return (1.f - e) * __builtin_amdgcn_rcpf(1.f + e);
}
__device__ __forceinline__ void split8v(float4v v0, float4v v1, half8& hi, half8& lo) {
#pragma unroll
    for (int j = 0; j < 4; ++j) {
        _Float16 h = (_Float16)v0[j];
        hi[j] = h; lo[j] = (_Float16)(v0[j] - (float)h);
    }
#pragma unroll
    for (int j = 0; j < 4; ++j) {
        _Float16 h = (_Float16)v1[j];
        hi[4 + j] = h; lo[4 + j] = (_Float16)(v1[j] - (float)h);
    }
}

// packed dual-fp32 FMA: p.xy += w.xy * h.xy  (exact fp32, 1 instr / 2 MACs)
#define PKFMA(p, w, h) \
    asm("v_pk_fma_f32 %0, %1, %2, %0" : "+v"(p) : "v"(w), "v"(h))

// ---------------------------------------------------------------------------
// Shared-memory layouts (union'd). LstmSh dominates: union 55KB -> 2 blk/CU.
// ---------------------------------------------------------------------------
struct LstmSh {
    float hbuf[2][544];     // 2 buffers x 4 bank-shifted copies(136)
    float Hseq[96 * 132];   // layer output sequence (padded rows)
};
struct GatSh {
    unsigned long long adjm[256];   // adj bitmask: row i -> adjm[2i],adjm[2i+1]
    float xv[128];
    float u1[32], v1[32], coef[4];
    float s1v[128];
    float h2s[128 * 33];
    float wh2[128 * 17];
    float Lv[128], Rv[128], rd2[128];
    float d_h[4][128], s_h[4][128];
};
union ShU { LstmSh l; GatSh g; };

// ---------------------------------------------------------------------------
// LSTM body: one block per batch element, 512 threads (r11 structure).
// proj = M=96 MFMA GEMM (split-fp16) -> Pre in global (L2).
// rec: thread = (hu, K-chunk c4 of 32K), 4 gate rows, 128 weight VGPRs,
//      pk_fma dot + shfl butterfly + redundant act, 1 barrier/step,
//      Pre(t+1) register prefetch.
// ---------------------------------------------------------------------------
__device__ __forceinline__ void lstm_body(LstmSh& sh, int b,
    const float* __restrict__ x,     // [16][96][128]
    const float* __restrict__ Wih,   // [3][512][128]
    const float* __restrict__ Whh,   // [3][512][128]
    const float* __restrict__ bih,   // [3][512]
    const float* __restrict__ bhh,   // [3][512]
    float* __restrict__ PreBase,     // this block: 3 * 96*512 floats
    float* __restrict__ xl_out)      // [16][128]
{
    int tid = threadIdx.x;
    int w = tid >> 6, lane = tid & 63, quad = lane >> 4, sub = lane & 15;

    // rec decomposition: hu = 16w + sub, K-chunk c = quad (32 K each)
    int hu = 16 * w + sub;
    int c4 = quad;

    __builtin_amdgcn_s_setprio(1);   // LSTM is the critical path when fused

    for (int layer = 0; layer < 3; ++layer) {
        const float* WihL = Wih + layer * 65536;
        const float* WhhL = Whh + layer * 65536;
        float* Pre = PreBase + layer * (96 * 512);

        // ======== proj GEMM (MFMA, split-fp16): Pre[t][r] = A[t].Wih[r]+bias
        {
            half8 bhi[4][4], blo[4][4];
            float bias[4];
#pragma unroll
            for (int tt = 0; tt < 4; ++tt) {
                int r = tt * 128 + 16 * w + sub;
                bias[tt] = bih[layer * 512 + r] + bhh[layer * 512 + r];
#pragma unroll
                for (int kc = 0; kc < 4; ++kc) {
                    const float4v* p = (const float4v*)(WihL + r * 128 + kc * 32 + quad * 8);
                    split8v(p[0], p[1], bhi[tt][kc], blo[tt][kc]);
                }
            }
            for (int mt = 0; mt < 6; ++mt) {
                half8 ahi[4], alo[4];
                if (layer == 0) {
                    const float* arow = x + b * 12288 + (mt * 16 + sub) * 128;
#pragma unroll
                    for (int kc = 0; kc < 4; ++kc) {
                        const float4v* p = (const float4v*)(arow + kc * 32 + quad * 8);
                        split8v(p[0], p[1], ahi[kc], alo[kc]);
                    }
                } else {
                    const float* arow = sh.Hseq + (mt * 16 + sub) * 132;
#pragma unroll
                    for (int kc = 0; kc < 4; ++kc) {
                        const float4v* p = (const float4v*)(arow + kc * 32 + quad * 8);
                        split8v(p[0], p[1], ahi[kc], alo[kc]);
                    }
                }
                floatx4 acc[4];
#pragma unroll
                for (int tt = 0; tt < 4; ++tt) {
                    floatx4 a = {bias[tt], bias[tt], bias[tt], bias[tt]};
                    acc[tt] = a;
                }
#pragma unroll
                for (int tt = 0; tt < 4; ++tt)
#pragma unroll
                    for (int kc = 0; kc < 4; ++kc) {
                        acc[tt] = __builtin_amdgcn_mfma_f32_16x16x32_f16(ahi[kc], bhi[tt][kc], acc[tt], 0, 0, 0);
                        acc[tt] = __builtin_amdgcn_mfma_f32_16x16x32_f16(ahi[kc], blo[tt][kc], acc[tt], 0, 0, 0);
                        acc[tt] = __builtin_amdgcn_mfma_f32_16x16x32_f16(alo[kc], bhi[tt][kc], acc[tt], 0, 0, 0);
                    }
                // store: timestep m = mt*16 + quad*4 + reg, row = tt*128+16w+sub
#pragma unroll
                for (int tt = 0; tt < 4; ++tt)
#pragma unroll
                    for (int reg = 0; reg < 4; ++reg)
                        Pre[(mt * 16 + quad * 4 + reg) * 512 + tt * 128 + 16 * w + sub] = acc[tt][reg];
            }
        }

        // ======== recurrence weights: 4 gate rows of hu, K in [32c, 32c+32)
        // stored as float2 halves of the r11 float4 layout (same bytes,
        // same 128 VGPRs); loads stay dwordx4.
        float2v wgt[4][16];
#pragma unroll
        for (int g = 0; g < 4; ++g) {
            const float4v* p = (const float4v*)(WhhL + (g * 128 + hu) * 128 + c4 * 32);
#pragma unroll
            for (int k = 0; k < 8; ++k) {
                float4v t4 = p[k];
                wgt[g][2 * k]     = __builtin_shufflevector(t4, t4, 0, 1);
                wgt[g][2 * k + 1] = __builtin_shufflevector(t4, t4, 2, 3);
            }
        }
        sh.hbuf[0][c4 * 136 + hu] = 0.f;   // zero all 4 copies of buffer 0
        float cvar = 0.f;
        __syncthreads();   // Pre stores drained; hbuf zeroed; Hseq reads done

        const float* PreHu = Pre + hu;
        float pre[4];
#pragma unroll
        for (int g = 0; g < 4; ++g) pre[g] = PreHu[g * 128];   // t=0

        for (int t = 0; t < 96; ++t) {
            int rb = t & 1, wb = rb ^ 1;
            // prefetch NEXT step's Pre: a full step of latency cover
            // (GAT's 100MB stream evicts L2 in the fused kernel)
            int tn = (t < 95) ? t + 1 : 95;
            float pren[4];
#pragma unroll
            for (int g = 0; g < 4; ++g)
                pren[g] = PreHu[tn * 512 + g * 128];

            // h chunk from this lane's bank-shifted copy: banks (8c+4k)%32,
            // distinct across c for fixed k -> conflict-free broadcast
            const float2v* hc2 = (const float2v*)(&sh.hbuf[rb][c4 * 168]);
            float2v pl[4], ph[4];
#pragma unroll
            for (int g = 0; g < 4; ++g) {
                float2v z = {0.f, 0.f};
                pl[g] = z; ph[g] = z;
            }
#pragma unroll
            for (int k = 0; k < 8; ++k) {
                float2v hl = hc2[2 * k], hh = hc2[2 * k + 1];
#pragma unroll
                for (int g = 0; g < 4; ++g) {
                    PKFMA(pl[g], wgt[g][2 * k],     hl);
                    PKFMA(ph[g], wgt[g][2 * k + 1], hh);
                }
            }
            float p[4];
#pragma unroll
            for (int g = 0; g < 4; ++g) {
                // same reduction order as r11's ((x+y)+z)+w
                float s = pl[g].x + pl[g].y + ph[g].x + ph[g].y;
                s += __shfl_xor(s, 16, 64);   // combine chunk pairs
                s += __shfl_xor(s, 32, 64);   // combine halves
                p[g] = s + pre[g];
            }
            // all 4 c-lanes compute identical activations (keeps cvar coherent)
            float c = sigm(p[1]) * cvar + sigm(p[0]) * tanhp(p[2]);
            cvar = c;
            float h = sigm(p[3]) * tanhp(c);
            sh.hbuf[wb][c4 * 136 + hu] = h;      // each lane updates its copy
            if (c4 == 0) {
                if (layer < 2) sh.Hseq[t * 132 + hu] = h;
                else if (t == 95) xl_out[b * 128 + hu] = h;
            }
#pragma unroll
            for (int g = 0; g < 4; ++g) pre[g] = pren[g];
            __syncthreads();   // h visible; all reads of rb complete
        }
        __syncthreads();
    }
    __builtin_amdgcn_s_setprio(0);
}

// ---------------------------------------------------------------------------
// GAT body: r11 VERBATIM. One block per graph (b,s), 512 threads.
// Ballot bitmask + single-pass no-max softmax + fused tile write.
// ---------------------------------------------------------------------------
__device__ __forceinline__ void gat_body(GatSh& s, int m,
    const float* __restrict__ x, const float* __restrict__ adj,
    const float* __restrict__ W_emb, const float* __restrict__ b_emb,
    const float* __restrict__ W1, const float* __restrict__ a1,
    const float* __restrict__ W2, const float* __restrict__ a2,
    float* __restrict__ attn_out, float* __restrict__ xg)
{
    int tid = threadIdx.x;

    // ---- stage: xv, adjacency bitmask (ballot), u1/v1
    if (tid < 128) s.xv[tid] = x[m * 128 + tid];
#pragma unroll
    for (int base = 0; base < 16384; base += 512) {
        int idx = base + tid;
        unsigned long long msk = __ballot(adj[idx] > 0.f);
        if ((tid & 63) == 0) s.adjm[idx >> 6] = msk;
    }
    if (tid < 32) {
        float su = 0.f, sv = 0.f;
        for (int kk = 0; kk < 32; ++kk) {
            float w1v = W1[kk * 32 + tid];
            su += W_emb[kk] * w1v;
            sv += b_emb[kk] * w1v;
        }
        s.u1[tid] = su; s.v1[tid] = sv;
    }
    __syncthreads();
    if (tid < 4) {
        const float* av = a1 + ((tid >= 2) ? 32 : 0);
        const float* uv = (tid & 1) ? s.v1 : s.u1;
        float sum = 0.f;
        for (int f = 0; f < 32; ++f) sum += uv[f] * av[f];
        s.coef[tid] = sum;
    }
    __syncthreads();
    float cL = s.coef[0], dL = s.coef[1], cR = s.coef[2], dR = s.coef[3];

    // ---- GAT1: single-pass den/wsum (no max: |e| bounded for this model)
    {
        int i = tid & 127, q = tid >> 7;   // q in [0,4): 32-wide j slice
        unsigned int ms = (unsigned int)(s.adjm[(i << 1) | (q >> 1)] >> ((q & 1) * 32));
        float Li = s.xv[i] * cL + dL;
        float den = 0.f, wsum = 0.f;
        int j0 = q * 32;
#pragma unroll
        for (int jj = 0; jj < 32; ++jj) {
            if ((ms >> jj) & 1) {
                float xj = s.xv[j0 + jj];
                float e = Li + xj * cR + dR;
                e = e > 0.f ? e : 0.2f * e;
                float p = fast_exp(e);
                den += p; wsum += p * xj;
            }
        }
        s.d_h[q][i] = den; s.s_h[q][i] = wsum;
    }
    __syncthreads();
    if (tid < 128) {
        float den = 0.f, wsum = 0.f;
#pragma unroll
        for (int q = 0; q < 4; ++q) { den += s.d_h[q][tid]; wsum += s.s_h[q][tid]; }
        s.s1v[tid] = wsum / den;
    }
    __syncthreads();
    // ---- h2 = elu(s1*u1 + v1)
#pragma unroll
    for (int e0 = 0; e0 < 4096; e0 += 512) {
        int e = e0 + tid;
        int i = e >> 5, f = e & 31;
        float v = s.s1v[i] * s.u1[f] + s.v1[f];
        s.h2s[i * 33 + f] = v > 0.f ? v : fast_exp(v) - 1.f;
    }
    __syncthreads();
    // ---- Wh2 = h2 @ W2  (128x32 @ 32x16), 4 threads/row
    {
        int i = tid >> 2, g0 = (tid & 3) * 4;
        float accv[4] = {0.f, 0.f, 0.f, 0.f};
        for (int f = 0; f < 32; ++f) {
            float hv = s.h2s[i * 33 + f];
#pragma unroll
            for (int g = 0; g < 4; ++g) accv[g] += hv * W2[f * 16 + g0 + g];
        }
#pragma unroll
        for (int g = 0; g < 4; ++g) s.wh2[i * 17 + g0 + g] = accv[g];
    }
    __syncthreads();
    if (tid < 256) {
        int i = tid & 127, which = tid >> 7;
        const float* aa = a2 + which * 16;
        float sum = 0.f;
#pragma unroll
        for (int g = 0; g < 16; ++g) sum += s.wh2[i * 17 + g] * aa[g];
        (which ? s.Rv : s.Lv)[i] = sum;
    }
    __syncthreads();
    // ---- attn2: single-pass den
    {
        int i = tid & 127, q = tid >> 7;
        unsigned int ms = (unsigned int)(s.adjm[(i << 1) | (q >> 1)] >> ((q & 1) * 32));
        float Li = s.Lv[i];
        float den = 0.f;
        int j0 = q * 32;
#pragma unroll
        for (int jj = 0; jj < 32; ++jj) {
            if ((ms >> jj) & 1) {
                float e = Li + s.Rv[j0 + jj];
                e = e > 0.f ? e : 0.2f * e;
                den += fast_exp(e);
            }
        }
        s.d_h[q][i] = den;
    }
    __syncthreads();
    if (tid < 128) {
        float den = 0.f;
#pragma unroll
        for (int q = 0; q < 4; ++q) den += s.d_h[q][tid];
        s.rd2[tid] = 1.0f / den;
    }
    __syncthreads();

    // ---- full 16384-float tile write (float4), mask from bitmask
    float* aout = attn_out + (size_t)m * 16384;
#pragma unroll
    for (int k = 0; k < 8; ++k) {
        int e0 = k * 2048 + tid * 4;
        int i = e0 >> 7, j0 = e0 & 127;
        unsigned int bits = (unsigned int)(s.adjm[(i << 1) | (j0 >> 6)] >> (j0 & 63)) & 0xFu;
        float Li = s.Lv[i], ri = s.rd2[i];
        float4v p;
#pragma unroll
        for (int u = 0; u < 4; ++u) {
            float pv = 0.f;
            if ((bits >> u) & 1) {
                float e = Li + s.Rv[j0 + u];
                e = e > 0.f ? e : 0.2f * e;
                pv = fast_exp(e) * ri;
            }
            p[u] = pv;
        }
        *(float4v*)(aout + e0) = p;
    }

    // out2 = attn2 @ Wh2 only for the last timestep of each batch -> global XG
    if (m % 96 == 95) {
        int b = m / 96;
        int i = tid >> 2, g0 = (tid & 3) * 4;
        unsigned long long mA = s.adjm[i << 1], mB = s.adjm[(i << 1) | 1];
        float Li = s.Lv[i], ri = s.rd2[i];
        float accv[4] = {0.f, 0.f, 0.f, 0.f};
        for (int j = 0; j < 128; ++j) {
            unsigned long long mm = (j < 64) ? mA : mB;
            if ((mm >> (j & 63)) & 1) {
                float e = Li + s.Rv[j];
                e = e > 0.f ? e : 0.2f * e;
                float p = fast_exp(e) * ri;
#pragma unroll
                for (int g = 0; g < 4; ++g) accv[g] += p * s.wh2[j * 17 + g0 + g];
            }
        }
#pragma unroll
        for (int g = 0; g < 4; ++g) xg[b * 2048 + i * 16 + g0 + g] = accv[g];
    }
}

// ---------------------------------------------------------------------------
// Fused kernel: blocks 0..15 LSTM, 16..1551 GAT.
// ---------------------------------------------------------------------------
__global__ __launch_bounds__(512, 2) void fused_kernel(
    const float* __restrict__ x, const float* __restrict__ adj,
    const float* __restrict__ W_emb, const float* __restrict__ b_emb,
    const float* __restrict__ W1, const float* __restrict__ a1,
    const float* __restrict__ W2, const float* __restrict__ a2,
    const float* __restrict__ Wih, const float* __restrict__ Whh,
    const float* __restrict__ bih, const float* __restrict__ bhh,
    float* __restrict__ Pre, float* __restrict__ xl_out,
    float* __restrict__ attn_out, float* __restrict__ xg)
{
    __shared__ ShU sh;
    int bb = blockIdx.x;
    if (bb < 16) {
        lstm_body(sh.l, bb, x, Wih, Whh, bih, bhh, Pre + bb * 147456, xl_out);
    } else {
        gat_body(sh.g, bb - 16, x, adj, W_emb, b_emb, W1, a1, W2, a2, attn_out, xg);
    }
}

// ---------------------------------------------------------------------------
// Heads (r11 verbatim)
// ---------------------------------------------------------------------------
__global__ __launch_bounds__(256) void head_partial_kernel(
    const float* __restrict__ xl, const float* __restrict__ xg,
    const float* __restrict__ W1, float* __restrict__ hp)
{
    int k = blockIdx.x >> 4, chunk = blockIdx.x & 15;
    int d = threadIdx.x & 63, bg = threadIdx.x >> 6;
    float acc[4] = {0.f, 0.f, 0.f, 0.f};
    int c0 = chunk * 136;
    for (int cc = c0; cc < c0 + 136; ++cc) {
        float wv = W1[(k * 2176 + cc) * 64 + d];
#pragma unroll
        for (int u = 0; u < 4; ++u) {
            int b = bg * 4 + u;
            float cv = (cc < 128) ? xl[b * 128 + cc] : xg[b * 2048 + cc - 128];
            acc[u] += wv * cv;
        }
    }
#pragma unroll
    for (int u = 0; u < 4; ++u)
        hp[(((k * 16 + chunk) * 16) + bg * 4 + u) * 64 + d] = acc[u];
}

__global__ __launch_bounds__(256) void head_final_kernel(
    const float* __restrict__ hp, const float* __restrict__ b1,
    const float* __restrict__ W2, const float* __restrict__ b2,
    const float* __restrict__ W3d, const float* __restrict__ b3d,
    const float* __restrict__ W3r, const float* __restrict__ b3r,
    const float* __restrict__ W3v, const float* __restrict__ b3v,
    float* __restrict__ out)
{
    __shared__ float h1s[3 * 16 * 64];
    __shared__ float h2s[3 * 16 * 32];
    int tid = threadIdx.x;
    for (int o = tid; o < 3072; o += 256) {
        int k = o >> 10, rem = o & 1023, b = rem >> 6, d = rem & 63;
        float s = b1[k * 64 + d];
        for (int ch = 0; ch < 16; ++ch)
            s += hp[(((k * 16 + ch) * 16) + b) * 64 + d];
        h1s[o] = fmaxf(s, 0.f);
    }
    __syncthreads();
    for (int o = tid; o < 1536; o += 256) {
        int k = o >> 9, rem = o & 511, b = rem >> 5, e = rem & 31;
        float s = b2[k * 32 + e];
        for (int dd = 0; dd < 64; ++dd)
            s += h1s[(k * 16 + b) * 64 + dd] * W2[(k * 64 + dd) * 32 + e];
        h2s[o] = fmaxf(s, 0.f);
    }
    __syncthreads();
    if (tid < 64) {
        if (tid < 16) {
            int b = tid; float s = b3d[0];
            for (int e = 0; e < 32; ++e) s += h2s[b * 32 + e] * W3d[e];
            out[b] = s;
        } else if (tid < 32) {
            int b = tid - 16; float s = b3r[0];
            for (int e = 0; e < 32; ++e) s += h2s[(16 + b) * 32 + e] * W3r[e];
            out[16 + b] = s;
        } else {
            int b = (tid - 32) >> 1, j = tid & 1; float s = b3v[j];
            for (int e = 0; e < 32; ++e) s += h2s[(32 + b) * 32 + e] * W3v[e * 2 + j];
            out[32 + b * 2 + j] = s;
        }
    }
}

// ---------------------------------------------------------------------------
extern "C" void kernel_launch(void* const* d_in, const int* in_sizes, int n_in,
                              void* d_out, int out_size, void* d_ws, size_t ws_size,
                              hipStream_t stream)
{
    const float* x     = (const float*)d_in[0];
    const float* adj   = (const float*)d_in[1];
    const float* W_emb = (const float*)d_in[2];
    const float* b_emb = (const float*)d_in[3];
    const float* W1    = (const float*)d_in[4];
    const float* a1    = (const float*)d_in[5];
    const float* W2    = (const float*)d_in[6];
    const float* a2    = (const float*)d_in[7];
    const float* Wih   = (const float*)d_in[8];
    const float* Whh   = (const float*)d_in[9];
    const float* bih   = (const float*)d_in[10];
    const float* bhh   = (const float*)d_in[11];
    const float* hW1   = (const float*)d_in[12];
    const float* hb1   = (const float*)d_in[13];
    const float* hW2   = (const float*)d_in[14];
    const float* hb2   = (const float*)d_in[15];
    const float* W3d   = (const float*)d_in[16];
    const float* b3d   = (const float*)d_in[17];
    const float* W3r   = (const float*)d_in[18];
    const float* b3r   = (const float*)d_in[19];
    const float* W3v   = (const float*)d_in[20];
    const float* b3v   = (const float*)d_in[21];

    float* out = (float*)d_out;
    float* wsf = (float*)d_ws;
    float* XG  = wsf;                   // 16*2048
    float* XL  = wsf + 32768;           // 16*128
    float* HP  = wsf + 34816;           // 3*16*16*64
    float* PRE = wsf + 83968;           // 16 * 3*96*512

    fused_kernel<<<1552, 512, 0, stream>>>(
        x, adj, W_emb, b_emb, W1, a1, W2, a2,
        Wih, Whh, bih, bhh, PRE, XL, out + 64, XG);
    head_partial_kernel<<<48, 256, 0, stream>>>(XL, XG, hW1, HP);
    head_final_kernel<<<1, 256, 0, stream>>>(HP, hb1, hW2, hb2, W3d, b3d, W3r, b3r, W3v, b3v, out);
}

// Round 8
// 375.518 us; speedup vs baseline: 1.6524x; 1.2807x over previous
//
#include <hip/hip_runtime.h>
#include <hip/hip_bf16.h>

// ---------------------------------------------------------------------------
// HybridGATLSTM on MI355X — round 14.
//   r13 post-mortem: pk_fma + b64 LDS reads regressed (+23us); step-cost
//   micro-optimization has failed twice. r11 (fused 290us) is the base.
//   Round 14 attacks the SEQUENTIAL STEP COUNT instead: the 3 LSTM layers
//   form a pipeline (layer l step t needs only layer l-1 step t), so the
//   LSTM becomes 48 blocks = 16 batches x 3 layers, chunk-pipelined at
//   16-step granularity:
//     L0 (blocks 0..15):  r11-verbatim layer-0 (full MFMA proj upfront,
//                         weights resident, 96 straight steps); publishes h
//                         per 16-step chunk via device-scope atomicExch +
//                         flag (atomics meet at the coherence point -> no
//                         cache-flush fences; r8-r10-proven handoff).
//     L1/L2 (16..47):     per chunk: spin flag -> stage h-chunk to LDS via
//                         atomic loads -> 1-mt MFMA proj -> LDS Pre ring ->
//                         reload rec weights -> 16 r11-verbatim steps.
//   Critical path ~ 96 + 32 steps + overheads ~ 145us vs 288 steps = 275us.
//   All arithmetic bit-identical to r11 -> absmax must stay 0.0001220703.
//   Deadlock-free: producers have the lowest block ids; all 48 LSTM blocks
//   are in the first dispatch wave (<512 slots).
//   GAT body (blocks 48..1583) and head kernels: r11 verbatim.
// ---------------------------------------------------------------------------

typedef _Float16 half8 __attribute__((ext_vector_type(8)));
typedef float floatx4 __attribute__((ext_vector_type(4)));
typedef float float4v __attribute__((ext_vector_type(4)));

#define LOG2E 1.44269504088896f

__device__ __forceinline__ float fast_exp(float x) {
    return __builtin_amdgcn_exp2f(x * LOG2E);
}
__device__ __forceinline__ float sigm(float x) {
    x = fminf(fmaxf(x, -30.f), 30.f);
    return __builtin_amdgcn_rcpf(1.f + __builtin_amdgcn_exp2f(-x * LOG2E));
}
__device__ __forceinline__ float tanhp(float x) {
    x = fminf(fmaxf(x, -15.f), 15.f);
    float e = __builtin_amdgcn_exp2f(-2.f * LOG2E * x);
    return (1.f - e) * __builtin_amdgcn_rcpf(1.f + e);
}
__device__ __forceinline__ void split8v(float4v v0, float4v v1, half8& hi, half8& lo) {
#pragma unroll
    for (int j = 0; j < 4; ++j) {
        _Float16 h = (_Float16)v0[j];
        hi[j] = h; lo[j] = (_Float16)(v0[j] - (float)h);
    }
#pragma unroll
    for (int j = 0; j < 4; ++j) {
        _Float16 h = (_Float16)v1[j];
        hi[4 + j] = h; lo[4 + j] = (_Float16)(v1[j] - (float)h);
    }
}

// ---------------------------------------------------------------------------
// Shared-memory layouts (union'd).
// LstmSh: hbuf 4.3KB + stage_in/out 2x8.25KB + PreL ring 32.25KB = 53KB.
// GatSh ~34.5KB. Union 53KB -> 2 blocks/CU (106KB <= 160KB).
// ---------------------------------------------------------------------------
struct LstmSh {
    float hbuf[2][544];       // 2 buffers x 4 bank-shifted copies(136)
    float stage_in[16 * 132]; // consumer: h-chunk from previous layer
    float stage_out[16 * 132];// producer: h-chunk to publish
    float PreL[16 * 516];     // L1/L2: Pre ring for current chunk (padded)
};
struct GatSh {
    unsigned long long adjm[256];
    float xv[128];
    float u1[32], v1[32], coef[4];
    float s1v[128];
    float h2s[128 * 33];
    float wh2[128 * 17];
    float Lv[128], Rv[128], rd2[128];
    float d_h[4][128], s_h[4][128];
};
union ShU { LstmSh l; GatSh g; };

// ---------------------------------------------------------------------------
// One LSTM layer per block, 512 threads. Chunk = 16 timesteps (1 mt tile).
// ---------------------------------------------------------------------------
__device__ __forceinline__ void lstm_layer_body(LstmSh& sh, int b, int layer,
    const float* __restrict__ x,     // [16][96][128]
    const float* __restrict__ Wih,   // [3][512][128]
    const float* __restrict__ Whh,   // [3][512][128]
    const float* __restrict__ bih,   // [3][512]
    const float* __restrict__ bhh,   // [3][512]
    float* __restrict__ Pre0,        // layer0 only: this batch, 96*512 floats
    const float* __restrict__ HseqIn,// layer>=1: [96][128] (atomic-written)
    float* __restrict__ HseqOut,     // layer<=1: [96][128]
    int* __restrict__ fIn,           // layer>=1: 6 chunk flags (producer's)
    int* __restrict__ fOut,          // layer<=1: 6 chunk flags (ours)
    float* __restrict__ xl_out)      // [16][128] (layer2 only)
{
    int tid = threadIdx.x;
    int w = tid >> 6, lane = tid & 63, quad = lane >> 4, sub = lane & 15;
    int hu = 16 * w + sub;
    int c4 = quad;
    const float* WihL = Wih + layer * 65536;
    const float* WhhL = Whh + layer * 65536;

    __builtin_amdgcn_s_setprio(1);

    if (layer == 0) {
        // ======== full proj upfront (r11 verbatim, A from x) -> global Pre
        {
            half8 bhi[4][4], blo[4][4];
            float bias[4];
#pragma unroll
            for (int tt = 0; tt < 4; ++tt) {
                int r = tt * 128 + 16 * w + sub;
                bias[tt] = bih[r] + bhh[r];
#pragma unroll
                for (int kc = 0; kc < 4; ++kc) {
                    const float4v* p = (const float4v*)(WihL + r * 128 + kc * 32 + quad * 8);
                    split8v(p[0], p[1], bhi[tt][kc], blo[tt][kc]);
                }
            }
            for (int mt = 0; mt < 6; ++mt) {
                half8 ahi[4], alo[4];
                const float* arow = x + b * 12288 + (mt * 16 + sub) * 128;
#pragma unroll
                for (int kc = 0; kc < 4; ++kc) {
                    const float4v* p = (const float4v*)(arow + kc * 32 + quad * 8);
                    split8v(p[0], p[1], ahi[kc], alo[kc]);
                }
                floatx4 acc[4];
#pragma unroll
                for (int tt = 0; tt < 4; ++tt) {
                    floatx4 a = {bias[tt], bias[tt], bias[tt], bias[tt]};
                    acc[tt] = a;
                }
#pragma unroll
                for (int tt = 0; tt < 4; ++tt)
#pragma unroll
                    for (int kc = 0; kc < 4; ++kc) {
                        acc[tt] = __builtin_amdgcn_mfma_f32_16x16x32_f16(ahi[kc], bhi[tt][kc], acc[tt], 0, 0, 0);
                        acc[tt] = __builtin_amdgcn_mfma_f32_16x16x32_f16(ahi[kc], blo[tt][kc], acc[tt], 0, 0, 0);
                        acc[tt] = __builtin_amdgcn_mfma_f32_16x16x32_f16(alo[kc], bhi[tt][kc], acc[tt], 0, 0, 0);
                    }
#pragma unroll
                for (int tt = 0; tt < 4; ++tt)
#pragma unroll
                    for (int reg = 0; reg < 4; ++reg)
                        Pre0[(mt * 16 + quad * 4 + reg) * 512 + tt * 128 + 16 * w + sub] = acc[tt][reg];
            }
        }
        // ======== rec: weights resident, 96 straight steps (r11 verbatim)
        float4v wgt[4][8];
#pragma unroll
        for (int g = 0; g < 4; ++g) {
            const float4v* p = (const float4v*)(WhhL + (g * 128 + hu) * 128 + c4 * 32);
#pragma unroll
            for (int k = 0; k < 8; ++k) wgt[g][k] = p[k];
        }
        sh.hbuf[0][c4 * 136 + hu] = 0.f;
        float cvar = 0.f;
        __syncthreads();

        for (int t = 0; t < 96; ++t) {
            int rb = t & 1, wb = rb ^ 1;
            float pre[4];
#pragma unroll
            for (int g = 0; g < 4; ++g)
                pre[g] = Pre0[t * 512 + g * 128 + hu];
            const float4v* hc = (const float4v*)(&sh.hbuf[rb][c4 * 168]);
            float4v p4[4];
#pragma unroll
            for (int g = 0; g < 4; ++g) { float4v z = {0.f,0.f,0.f,0.f}; p4[g] = z; }
#pragma unroll
            for (int k = 0; k < 8; ++k) {
                float4v hv = hc[k];
#pragma unroll
                for (int g = 0; g < 4; ++g) p4[g] += wgt[g][k] * hv;
            }
            float p[4];
#pragma unroll
            for (int g = 0; g < 4; ++g) {
                float s = p4[g].x + p4[g].y + p4[g].z + p4[g].w;
                s += __shfl_xor(s, 16, 64);
                s += __shfl_xor(s, 32, 64);
                p[g] = s + pre[g];
            }
            float c = sigm(p[1]) * cvar + sigm(p[0]) * tanhp(p[2]);
            cvar = c;
            float h = sigm(p[3]) * tanhp(c);
            sh.hbuf[wb][c4 * 136 + hu] = h;
            if (c4 == 0) sh.stage_out[(t & 15) * 132 + hu] = h;
            __syncthreads();
            if ((t & 15) == 15) {
                // publish chunk: device-scope atomics land at coherence point
                int k = t >> 4;
                float* outp = HseqOut + k * 2048;
#pragma unroll
                for (int u = 0; u < 4; ++u) {
                    int e = tid * 4 + u;
                    atomicExch(&outp[e], sh.stage_out[(e >> 7) * 132 + (e & 127)]);
                }
                __syncthreads();   // all atomics drained (per-wave vmcnt)
                if (tid == 0) atomicExch(&fOut[k], 1);
            }
        }
    } else {
        // ======== layers 1,2: chunk-pipelined consumer
        float bias[4];
#pragma unroll
        for (int tt = 0; tt < 4; ++tt) {
            int r = tt * 128 + 16 * w + sub;
            bias[tt] = bih[layer * 512 + r] + bhh[layer * 512 + r];
        }
        sh.hbuf[0][c4 * 136 + hu] = 0.f;
        float cvar = 0.f;
        __syncthreads();

        for (int k = 0; k < 6; ++k) {
            if (tid == 0) {
                while (atomicAdd(&fIn[k], 0) == 0) __builtin_amdgcn_s_sleep(16);
            }
            __syncthreads();
            // ---- stage h-chunk: atomic loads fetch from coherence point
            {
                const float* inp = HseqIn + k * 2048;
#pragma unroll
                for (int u = 0; u < 4; ++u) {
                    int e = tid * 4 + u;
                    sh.stage_in[(e >> 7) * 132 + (e & 127)] =
                        atomicAdd((float*)&inp[e], 0.f);
                }
            }
            __syncthreads();
            // ---- proj for mt = k (one 16-step tile) -> LDS Pre ring
            {
                half8 bhi[4][4], blo[4][4];
#pragma unroll
                for (int tt = 0; tt < 4; ++tt) {
                    int r = tt * 128 + 16 * w + sub;
#pragma unroll
                    for (int kc = 0; kc < 4; ++kc) {
                        const float4v* p = (const float4v*)(WihL + r * 128 + kc * 32 + quad * 8);
                        split8v(p[0], p[1], bhi[tt][kc], blo[tt][kc]);
                    }
                }
                half8 ahi[4], alo[4];
                const float* arow = &sh.stage_in[sub * 132];
#pragma unroll
                for (int kc = 0; kc < 4; ++kc) {
                    const float4v* p = (const float4v*)(arow + kc * 32 + quad * 8);
                    split8v(p[0], p[1], ahi[kc], alo[kc]);
                }
                floatx4 acc[4];
#pragma unroll
                for (int tt = 0; tt < 4; ++tt) {
                    floatx4 a = {bias[tt], bias[tt], bias[tt], bias[tt]};
                    acc[tt] = a;
                }
#pragma unroll
                for (int tt = 0; tt < 4; ++tt)
#pragma unroll
                    for (int kc = 0; kc < 4; ++kc) {
                        acc[tt] = __builtin_amdgcn_mfma_f32_16x16x32_f16(ahi[kc], bhi[tt][kc], acc[tt], 0, 0, 0);
                        acc[tt] = __builtin_amdgcn_mfma_f32_16x16x32_f16(ahi[kc], blo[tt][kc], acc[tt], 0, 0, 0);
                        acc[tt] = __builtin_amdgcn_mfma_f32_16x16x32_f16(alo[kc], bhi[tt][kc], acc[tt], 0, 0, 0);
                    }
#pragma unroll
                for (int tt = 0; tt < 4; ++tt)
#pragma unroll
                    for (int reg = 0; reg < 4; ++reg)
                        sh.PreL[(quad * 4 + reg) * 516 + tt * 128 + 16 * w + sub] = acc[tt][reg];
            }
            __syncthreads();
            // ---- reload rec weights (proj B-frags freed -> same registers)
            float4v wgt[4][8];
#pragma unroll
            for (int g = 0; g < 4; ++g) {
                const float4v* p = (const float4v*)(WhhL + (g * 128 + hu) * 128 + c4 * 32);
#pragma unroll
                for (int kk = 0; kk < 8; ++kk) wgt[g][kk] = p[kk];
            }
            // ---- 16 rec steps (r11 verbatim, Pre from LDS ring)
            for (int tl = 0; tl < 16; ++tl) {
                int t = k * 16 + tl;
                int rb = t & 1, wb = rb ^ 1;
                float pre[4];
#pragma unroll
                for (int g = 0; g < 4; ++g)
                    pre[g] = sh.PreL[tl * 516 + g * 128 + hu];
                const float4v* hc = (const float4v*)(&sh.hbuf[rb][c4 * 168]);
                float4v p4[4];
#pragma unroll
                for (int g = 0; g < 4; ++g) { float4v z = {0.f,0.f,0.f,0.f}; p4[g] = z; }
#pragma unroll
                for (int kk = 0; kk < 8; ++kk) {
                    float4v hv = hc[kk];
#pragma unroll
                    for (int g = 0; g < 4; ++g) p4[g] += wgt[g][kk] * hv;
                }
                float p[4];
#pragma unroll
                for (int g = 0; g < 4; ++g) {
                    float s = p4[g].x + p4[g].y + p4[g].z + p4[g].w;
                    s += __shfl_xor(s, 16, 64);
                    s += __shfl_xor(s, 32, 64);
                    p[g] = s + pre[g];
                }
                float c = sigm(p[1]) * cvar + sigm(p[0]) * tanhp(p[2]);
                cvar = c;
                float h = sigm(p[3]) * tanhp(c);
                sh.hbuf[wb][c4 * 136 + hu] = h;
                if (c4 == 0) {
                    if (layer == 1) sh.stage_out[tl * 132 + hu] = h;
                    else if (t == 95) xl_out[b * 128 + hu] = h;
                }
                __syncthreads();
            }
            if (layer == 1) {
                float* outp = HseqOut + k * 2048;
#pragma unroll
                for (int u = 0; u < 4; ++u) {
                    int e = tid * 4 + u;
                    atomicExch(&outp[e], sh.stage_out[(e >> 7) * 132 + (e & 127)]);
                }
                __syncthreads();
                if (tid == 0) atomicExch(&fOut[k], 1);
            }
        }
    }
    __builtin_amdgcn_s_setprio(0);
}

// ---------------------------------------------------------------------------
// GAT body: r11 VERBATIM. One block per graph (b,s), 512 threads.
// ---------------------------------------------------------------------------
__device__ __forceinline__ void gat_body(GatSh& s, int m,
    const float* __restrict__ x, const float* __restrict__ adj,
    const float* __restrict__ W_emb, const float* __restrict__ b_emb,
    const float* __restrict__ W1, const float* __restrict__ a1,
    const float* __restrict__ W2, const float* __restrict__ a2,
    float* __restrict__ attn_out, float* __restrict__ xg)
{
    int tid = threadIdx.x;

    if (tid < 128) s.xv[tid] = x[m * 128 + tid];
#pragma unroll
    for (int base = 0; base < 16384; base += 512) {
        int idx = base + tid;
        unsigned long long msk = __ballot(adj[idx] > 0.f);
        if ((tid & 63) == 0) s.adjm[idx >> 6] = msk;
    }
    if (tid < 32) {
        float su = 0.f, sv = 0.f;
        for (int kk = 0; kk < 32; ++kk) {
            float w1v = W1[kk * 32 + tid];
            su += W_emb[kk] * w1v;
            sv += b_emb[kk] * w1v;
        }
        s.u1[tid] = su; s.v1[tid] = sv;
    }
    __syncthreads();
    if (tid < 4) {
        const float* av = a1 + ((tid >= 2) ? 32 : 0);
        const float* uv = (tid & 1) ? s.v1 : s.u1;
        float sum = 0.f;
        for (int f = 0; f < 32; ++f) sum += uv[f] * av[f];
        s.coef[tid] = sum;
    }
    __syncthreads();
    float cL = s.coef[0], dL = s.coef[1], cR = s.coef[2], dR = s.coef[3];

    {
        int i = tid & 127, q = tid >> 7;
        unsigned int ms = (unsigned int)(s.adjm[(i << 1) | (q >> 1)] >> ((q & 1) * 32));
        float Li = s.xv[i] * cL + dL;
        float den = 0.f, wsum = 0.f;
        int j0 = q * 32;
#pragma unroll
        for (int jj = 0; jj < 32; ++jj) {
            if ((ms >> jj) & 1) {
                float xj = s.xv[j0 + jj];
                float e = Li + xj * cR + dR;
                e = e > 0.f ? e : 0.2f * e;
                float p = fast_exp(e);
                den += p; wsum += p * xj;
            }
        }
        s.d_h[q][i] = den; s.s_h[q][i] = wsum;
    }
    __syncthreads();
    if (tid < 128) {
        float den = 0.f, wsum = 0.f;
#pragma unroll
        for (int q = 0; q < 4; ++q) { den += s.d_h[q][tid]; wsum += s.s_h[q][tid]; }
        s.s1v[tid] = wsum / den;
    }
    __syncthreads();
#pragma unroll
    for (int e0 = 0; e0 < 4096; e0 += 512) {
        int e = e0 + tid;
        int i = e >> 5, f = e & 31;
        float v = s.s1v[i] * s.u1[f] + s.v1[f];
        s.h2s[i * 33 + f] = v > 0.f ? v : fast_exp(v) - 1.f;
    }
    __syncthreads();
    {
        int i = tid >> 2, g0 = (tid & 3) * 4;
        float accv[4] = {0.f, 0.f, 0.f, 0.f};
        for (int f = 0; f < 32; ++f) {
            float hv = s.h2s[i * 33 + f];
#pragma unroll
            for (int g = 0; g < 4; ++g) accv[g] += hv * W2[f * 16 + g0 + g];
        }
#pragma unroll
        for (int g = 0; g < 4; ++g) s.wh2[i * 17 + g0 + g] = accv[g];
    }
    __syncthreads();
    if (tid < 256) {
        int i = tid & 127, which = tid >> 7;
        const float* aa = a2 + which * 16;
        float sum = 0.f;
#pragma unroll
        for (int g = 0; g < 16; ++g) sum += s.wh2[i * 17 + g] * aa[g];
        (which ? s.Rv : s.Lv)[i] = sum;
    }
    __syncthreads();
    {
        int i = tid & 127, q = tid >> 7;
        unsigned int ms = (unsigned int)(s.adjm[(i << 1) | (q >> 1)] >> ((q & 1) * 32));
        float Li = s.Lv[i];
        float den = 0.f;
        int j0 = q * 32;
#pragma unroll
        for (int jj = 0; jj < 32; ++jj) {
            if ((ms >> jj) & 1) {
                float e = Li + s.Rv[j0 + jj];
                e = e > 0.f ? e : 0.2f * e;
                den += fast_exp(e);
            }
        }
        s.d_h[q][i] = den;
    }
    __syncthreads();
    if (tid < 128) {
        float den = 0.f;
#pragma unroll
        for (int q = 0; q < 4; ++q) den += s.d_h[q][tid];
        s.rd2[tid] = 1.0f / den;
    }
    __syncthreads();

    float* aout = attn_out + (size_t)m * 16384;
#pragma unroll
    for (int k = 0; k < 8; ++k) {
        int e0 = k * 2048 + tid * 4;
        int i = e0 >> 7, j0 = e0 & 127;
        unsigned int bits = (unsigned int)(s.adjm[(i << 1) | (j0 >> 6)] >> (j0 & 63)) & 0xFu;
        float Li = s.Lv[i], ri = s.rd2[i];
        float4v p;
#pragma unroll
        for (int u = 0; u < 4; ++u) {
            float pv = 0.f;
            if ((bits >> u) & 1) {
                float e = Li + s.Rv[j0 + u];
                e = e > 0.f ? e : 0.2f * e;
                pv = fast_exp(e) * ri;
            }
            p[u] = pv;
        }
        *(float4v*)(aout + e0) = p;
    }

    if (m % 96 == 95) {
        int b = m / 96;
        int i = tid >> 2, g0 = (tid & 3) * 4;
        unsigned long long mA = s.adjm[i << 1], mB = s.adjm[(i << 1) | 1];
        float Li = s.Lv[i], ri = s.rd2[i];
        float accv[4] = {0.f, 0.f, 0.f, 0.f};
        for (int j = 0; j < 128; ++j) {
            unsigned long long mm = (j < 64) ? mA : mB;
            if ((mm >> (j & 63)) & 1) {
                float e = Li + s.Rv[j];
                e = e > 0.f ? e : 0.2f * e;
                float p = fast_exp(e) * ri;
#pragma unroll
                for (int g = 0; g < 4; ++g) accv[g] += p * s.wh2[j * 17 + g0 + g];
            }
        }
#pragma unroll
        for (int g = 0; g < 4; ++g) xg[b * 2048 + i * 16 + g0 + g] = accv[g];
    }
}

// ---------------------------------------------------------------------------
// Fused kernel: blocks 0..47 LSTM (layer = bb>>4, batch = bb&15; producers
// first), 48..1583 GAT.
// ---------------------------------------------------------------------------
__global__ __launch_bounds__(512, 2) void fused_kernel(
    const float* __restrict__ x, const float* __restrict__ adj,
    const float* __restrict__ W_emb, const float* __restrict__ b_emb,
    const float* __restrict__ W1, const float* __restrict__ a1,
    const float* __restrict__ W2, const float* __restrict__ a2,
    const float* __restrict__ Wih, const float* __restrict__ Whh,
    const float* __restrict__ bih, const float* __restrict__ bhh,
    float* __restrict__ Pre, float* __restrict__ Hseq,
    int* __restrict__ flags, float* __restrict__ xl_out,
    float* __restrict__ attn_out, float* __restrict__ xg)
{
    __shared__ ShU sh;
    int bb = blockIdx.x;
    if (bb < 48) {
        int layer = bb >> 4, b = bb & 15;
        float* Pre0 = Pre + b * 49152;
        const float* HseqIn = (layer >= 1) ? Hseq + ((layer - 1) * 16 + b) * 12288 : nullptr;
        float* HseqOut = (layer <= 1) ? Hseq + (layer * 16 + b) * 12288 : nullptr;
        int* fIn  = (layer >= 1) ? flags + ((layer - 1) * 16 + b) * 8 : nullptr;
        int* fOut = (layer <= 1) ? flags + (layer * 16 + b) * 8 : nullptr;
        lstm_layer_body(sh.l, b, layer, x, Wih, Whh, bih, bhh,
                        Pre0, HseqIn, HseqOut, fIn, fOut, xl_out);
    } else {
        gat_body(sh.g, bb - 48, x, adj, W_emb, b_emb, W1, a1, W2, a2, attn_out, xg);
    }
}

// ---------------------------------------------------------------------------
// Heads (r11 verbatim)
// ---------------------------------------------------------------------------
__global__ __launch_bounds__(256) void head_partial_kernel(
    const float* __restrict__ xl, const float* __restrict__ xg,
    const float* __restrict__ W1, float* __restrict__ hp)
{
    int k = blockIdx.x >> 4, chunk = blockIdx.x & 15;
    int d = threadIdx.x & 63, bg = threadIdx.x >> 6;
    float acc[4] = {0.f, 0.f, 0.f, 0.f};
    int c0 = chunk * 136;
    for (int cc = c0; cc < c0 + 136; ++cc) {
        float wv = W1[(k * 2176 + cc) * 64 + d];
#pragma unroll
        for (int u = 0; u < 4; ++u) {
            int b = bg * 4 + u;
            float cv = (cc < 128) ? xl[b * 128 + cc] : xg[b * 2048 + cc - 128];
            acc[u] += wv * cv;
        }
    }
#pragma unroll
    for (int u = 0; u < 4; ++u)
        hp[(((k * 16 + chunk) * 16) + bg * 4 + u) * 64 + d] = acc[u];
}

__global__ __launch_bounds__(256) void head_final_kernel(
    const float* __restrict__ hp, const float* __restrict__ b1,
    const float* __restrict__ W2, const float* __restrict__ b2,
    const float* __restrict__ W3d, const float* __restrict__ b3d,
    const float* __restrict__ W3r, const float* __restrict__ b3r,
    const float* __restrict__ W3v, const float* __restrict__ b3v,
    float* __restrict__ out)
{
    __shared__ float h1s[3 * 16 * 64];
    __shared__ float h2s[3 * 16 * 32];
    int tid = threadIdx.x;
    for (int o = tid; o < 3072; o += 256) {
        int k = o >> 10, rem = o & 1023, b = rem >> 6, d = rem & 63;
        float s = b1[k * 64 + d];
        for (int ch = 0; ch < 16; ++ch)
            s += hp[(((k * 16 + ch) * 16) + b) * 64 + d];
        h1s[o] = fmaxf(s, 0.f);
    }
    __syncthreads();
    for (int o = tid; o < 1536; o += 256) {
        int k = o >> 9, rem = o & 511, b = rem >> 5, e = rem & 31;
        float s = b2[k * 32 + e];
        for (int dd = 0; dd < 64; ++dd)
            s += h1s[(k * 16 + b) * 64 + dd] * W2[(k * 64 + dd) * 32 + e];
        h2s[o] = fmaxf(s, 0.f);
    }
    __syncthreads();
    if (tid < 64) {
        if (tid < 16) {
            int b = tid; float s = b3d[0];
            for (int e = 0; e < 32; ++e) s += h2s[b * 32 + e] * W3d[e];
            out[b] = s;
        } else if (tid < 32) {
            int b = tid - 16; float s = b3r[0];
            for (int e = 0; e < 32; ++e) s += h2s[(16 + b) * 32 + e] * W3r[e];
            out[16 + b] = s;
        } else {
            int b = (tid - 32) >> 1, j = tid & 1; float s = b3v[j];
            for (int e = 0; e < 32; ++e) s += h2s[(32 + b) * 32 + e] * W3v[e * 2 + j];
            out[32 + b * 2 + j] = s;
        }
    }
}

// ---------------------------------------------------------------------------
extern "C" void kernel_launch(void* const* d_in, const int* in_sizes, int n_in,
                              void* d_out, int out_size, void* d_ws, size_t ws_size,
                              hipStream_t stream)
{
    const float* x     = (const float*)d_in[0];
    const float* adj   = (const float*)d_in[1];
    const float* W_emb = (const float*)d_in[2];
    const float* b_emb = (const float*)d_in[3];
    const float* W1    = (const float*)d_in[4];
    const float* a1    = (const float*)d_in[5];
    const float* W2    = (const float*)d_in[6];
    const float* a2    = (const float*)d_in[7];
    const float* Wih   = (const float*)d_in[8];
    const float* Whh   = (const float*)d_in[9];
    const float* bih   = (const float*)d_in[10];
    const float* bhh   = (const float*)d_in[11];
    const float* hW1   = (const float*)d_in[12];
    const float* hb1   = (const float*)d_in[13];
    const float* hW2   = (const float*)d_in[14];
    const float* hb2   = (const float*)d_in[15];
    const float* W3d   = (const float*)d_in[16];
    const float* b3d   = (const float*)d_in[17];
    const float* W3r   = (const float*)d_in[18];
    const float* b3r   = (const float*)d_in[19];
    const float* W3v   = (const float*)d_in[20];
    const float* b3v   = (const float*)d_in[21];

    float* out = (float*)d_out;
    float* wsf = (float*)d_ws;
    float* XG    = wsf;                   // 16*2048            = 32768
    float* XL    = wsf + 32768;           // 16*128             = 2048
    float* HP    = wsf + 34816;           // 3*16*16*64         = 49152
    int*   FLAGS = (int*)(wsf + 83968);   // 32*8 ints          (1 KB)
    float* PRE   = wsf + 84224;           // 16 * 96*512        = 786432
    float* HSEQ  = wsf + 870656;          // 32 * 96*128        = 393216
    // total 1,263,872 floats ~= 5.06 MB (< ws proven >= 9.77 MB in r7)

    hipMemsetAsync(FLAGS, 0, 32 * 8 * sizeof(int), stream);
    fused_kernel<<<1584, 512, 0, stream>>>(
        x, adj, W_emb, b_emb, W1, a1, W2, a2,
        Wih, Whh, bih, bhh, PRE, HSEQ, FLAGS, XL, out + 64, XG);
    head_partial_kernel<<<48, 256, 0, stream>>>(XL, XG, hW1, HP);
    head_final_kernel<<<1, 256, 0, stream>>>(HP, hb1, hW2, hb2, W3d, b3d, W3r, b3r, W3v, b3v, out);
}

// Round 9
// 353.085 us; speedup vs baseline: 1.7574x; 1.0635x over previous
//
#include <hip/hip_runtime.h>
#include <hip/hip_bf16.h>

// ---------------------------------------------------------------------------
// HybridGATLSTM on MI355X — round 15.
//   r14 (fused 203us) proved the layer pipeline; its residual ~75us is the
//   per-chunk B-frag + rec-weight RELOADS inside L1/L2 (both are 128-VGPR
//   sets; they cannot coexist). Round 15 wave-specializes:
//     per batch: L0rec(0..15) -> [L1proj(16..31) -> L1rec(32..47)]
//                             -> [L2proj(48..63) -> L2rec(64..79)]
//     proj blocks hold Wih B-frags resident forever; rec blocks hold rec
//     weights resident forever; nobody reloads anything per chunk.
//     Pre flows proj->rec through a 3-deep global ring (plain stores +
//     threadfence + flag; consumer flag-acquire + threadfence invalidates
//     its L1 -> safe ring reuse; WAR guarded by a consumed counter).
//     h flows rec->proj via the r14-proven atomicExch/atomicAdd pattern.
//   All arithmetic bit-identical to r11/r14: absmax must stay 0.0001220703.
//   GAT (blocks 80..1615) and head kernels: r11 verbatim.
//   Workspace: 2,051,072 floats = 8.2MB < 9.77MB proven available (r7).
// ---------------------------------------------------------------------------

typedef _Float16 half8 __attribute__((ext_vector_type(8)));
typedef float floatx4 __attribute__((ext_vector_type(4)));
typedef float float4v __attribute__((ext_vector_type(4)));

#define LOG2E 1.44269504088896f

__device__ __forceinline__ float fast_exp(float x) {
    return __builtin_amdgcn_exp2f(x * LOG2E);
}
__device__ __forceinline__ float sigm(float x) {
    x = fminf(fmaxf(x, -30.f), 30.f);
    return __builtin_amdgcn_rcpf(1.f + __builtin_amdgcn_exp2f(-x * LOG2E));
}
__device__ __forceinline__ float tanhp(float x) {
    x = fminf(fmaxf(x, -15.f), 15.f);
    float e = __builtin_amdgcn_exp2f(-2.f * LOG2E * x);
    return (1.f - e) * __builtin_amdgcn_rcpf(1.f + e);
}
__device__ __forceinline__ void split8v(float4v v0, float4v v1, half8& hi, half8& lo) {
#pragma unroll
    for (int j = 0; j < 4; ++j) {
        _Float16 h = (_Float16)v0[j];
        hi[j] = h; lo[j] = (_Float16)(v0[j] - (float)h);
    }
#pragma unroll
    for (int j = 0; j < 4; ++j) {
        _Float16 h = (_Float16)v1[j];
        hi[4 + j] = h; lo[4 + j] = (_Float16)(v1[j] - (float)h);
    }
}

// ---------------------------------------------------------------------------
// Shared-memory layouts (union'd). LstmSh 12.5KB, GatSh ~34.5KB -> union 35KB.
// ---------------------------------------------------------------------------
struct LstmSh {
    float hbuf[2][544];     // 2 buffers x 4 bank-shifted copies(136)
    float stage[16 * 132];  // h-chunk staging (out for rec, in for proj)
};
struct GatSh {
    unsigned long long adjm[256];
    float xv[128];
    float u1[32], v1[32], coef[4];
    float s1v[128];
    float h2s[128 * 33];
    float wh2[128 * 17];
    float Lv[128], Rv[128], rd2[128];
    float d_h[4][128], s_h[4][128];
};
union ShU { LstmSh l; GatSh g; };

// ---------------------------------------------------------------------------
// L0 block: full proj upfront (private Pre0), 96 straight rec steps,
// publish h per 16-step chunk (r14-verbatim pattern).
// ---------------------------------------------------------------------------
__device__ __forceinline__ void l0_body(LstmSh& sh, int b,
    const float* __restrict__ x, const float* __restrict__ Wih,
    const float* __restrict__ Whh, const float* __restrict__ bih,
    const float* __restrict__ bhh,
    float* __restrict__ Pre0,        // [96*512], private to this block
    float* __restrict__ Hout,        // [96][128] (atomic-published)
    int* __restrict__ fHout)         // 6 chunk flags
{
    int tid = threadIdx.x;
    int w = tid >> 6, lane = tid & 63, quad = lane >> 4, sub = lane & 15;
    int hu = 16 * w + sub, c4 = quad;

    __builtin_amdgcn_s_setprio(1);
    // ---- full proj (r11 verbatim, layer 0)
    {
        half8 bhi[4][4], blo[4][4];
        float bias[4];
#pragma unroll
        for (int tt = 0; tt < 4; ++tt) {
            int r = tt * 128 + 16 * w + sub;
            bias[tt] = bih[r] + bhh[r];
#pragma unroll
            for (int kc = 0; kc < 4; ++kc) {
                const float4v* p = (const float4v*)(Wih + r * 128 + kc * 32 + quad * 8);
                split8v(p[0], p[1], bhi[tt][kc], blo[tt][kc]);
            }
        }
        for (int mt = 0; mt < 6; ++mt) {
            half8 ahi[4], alo[4];
            const float* arow = x + b * 12288 + (mt * 16 + sub) * 128;
#pragma unroll
            for (int kc = 0; kc < 4; ++kc) {
                const float4v* p = (const float4v*)(arow + kc * 32 + quad * 8);
                split8v(p[0], p[1], ahi[kc], alo[kc]);
            }
            floatx4 acc[4];
#pragma unroll
            for (int tt = 0; tt < 4; ++tt) {
                floatx4 a = {bias[tt], bias[tt], bias[tt], bias[tt]};
                acc[tt] = a;
            }
#pragma unroll
            for (int tt = 0; tt < 4; ++tt)
#pragma unroll
                for (int kc = 0; kc < 4; ++kc) {
                    acc[tt] = __builtin_amdgcn_mfma_f32_16x16x32_f16(ahi[kc], bhi[tt][kc], acc[tt], 0, 0, 0);
                    acc[tt] = __builtin_amdgcn_mfma_f32_16x16x32_f16(ahi[kc], blo[tt][kc], acc[tt], 0, 0, 0);
                    acc[tt] = __builtin_amdgcn_mfma_f32_16x16x32_f16(alo[kc], bhi[tt][kc], acc[tt], 0, 0, 0);
                }
#pragma unroll
            for (int tt = 0; tt < 4; ++tt)
#pragma unroll
                for (int reg = 0; reg < 4; ++reg)
                    Pre0[(mt * 16 + quad * 4 + reg) * 512 + tt * 128 + 16 * w + sub] = acc[tt][reg];
        }
    }
    // ---- rec: weights resident, 96 steps (r11 verbatim) + chunk publish
    float4v wgt[4][8];
#pragma unroll
    for (int g = 0; g < 4; ++g) {
        const float4v* p = (const float4v*)(Whh + (g * 128 + hu) * 128 + c4 * 32);
#pragma unroll
        for (int k = 0; k < 8; ++k) wgt[g][k] = p[k];
    }
    sh.hbuf[0][c4 * 136 + hu] = 0.f;
    float cvar = 0.f;
    __syncthreads();

    for (int t = 0; t < 96; ++t) {
        int rb = t & 1, wb = rb ^ 1;
        float pre[4];
#pragma unroll
        for (int g = 0; g < 4; ++g)
            pre[g] = Pre0[t * 512 + g * 128 + hu];
        const float4v* hc = (const float4v*)(&sh.hbuf[rb][c4 * 168]);
        float4v p4[4];
#pragma unroll
        for (int g = 0; g < 4; ++g) { float4v z = {0.f,0.f,0.f,0.f}; p4[g] = z; }
#pragma unroll
        for (int k = 0; k < 8; ++k) {
            float4v hv = hc[k];
#pragma unroll
            for (int g = 0; g < 4; ++g) p4[g] += wgt[g][k] * hv;
        }
        float p[4];
#pragma unroll
        for (int g = 0; g < 4; ++g) {
            float s = p4[g].x + p4[g].y + p4[g].z + p4[g].w;
            s += __shfl_xor(s, 16, 64);
            s += __shfl_xor(s, 32, 64);
            p[g] = s + pre[g];
        }
        float c = sigm(p[1]) * cvar + sigm(p[0]) * tanhp(p[2]);
        cvar = c;
        float h = sigm(p[3]) * tanhp(c);
        sh.hbuf[wb][c4 * 136 + hu] = h;
        if (c4 == 0) sh.stage[(t & 15) * 132 + hu] = h;
        __syncthreads();
        if ((t & 15) == 15) {
            int k = t >> 4;
            float* outp = Hout + k * 2048;
#pragma unroll
            for (int u = 0; u < 4; ++u) {
                int e = tid * 4 + u;
                atomicExch(&outp[e], sh.stage[(e >> 7) * 132 + (e & 127)]);
            }
            __syncthreads();
            if (tid == 0) atomicExch(&fHout[k], 1);
        }
    }
    __builtin_amdgcn_s_setprio(0);
}

// ---------------------------------------------------------------------------
// Proj block (layers 1,2): Wih B-frags resident across all chunks.
// Per chunk: spin h flag -> atomic-stage h -> MFMA -> Pre ring (plain stores
// + fence + flag). Ring WAR: wait consumer's progress counter.
// ---------------------------------------------------------------------------
__device__ __forceinline__ void proj_body(LstmSh& sh, int layer,
    const float* __restrict__ Wih, const float* __restrict__ bih,
    const float* __restrict__ bhh,
    const float* __restrict__ Hin,   // [96][128] (atomic-written by producer)
    int* __restrict__ fH,            // producer's 6 flags
    float* __restrict__ PreRing,     // 3 * 16*512
    int* __restrict__ fP,            // our 6 flags
    int* __restrict__ cons)          // consumer progress counter
{
    int tid = threadIdx.x;
    int w = tid >> 6, lane = tid & 63, quad = lane >> 4, sub = lane & 15;
    const float* WihL = Wih + layer * 65536;

    half8 bhi[4][4], blo[4][4];
    float bias[4];
#pragma unroll
    for (int tt = 0; tt < 4; ++tt) {
        int r = tt * 128 + 16 * w + sub;
        bias[tt] = bih[layer * 512 + r] + bhh[layer * 512 + r];
#pragma unroll
        for (int kc = 0; kc < 4; ++kc) {
            const float4v* p = (const float4v*)(WihL + r * 128 + kc * 32 + quad * 8);
            split8v(p[0], p[1], bhi[tt][kc], blo[tt][kc]);
        }
    }
    for (int k = 0; k < 6; ++k) {
        if (tid == 0) {
            while (atomicAdd(&fH[k], 0) == 0) __builtin_amdgcn_s_sleep(16);
        }
        __syncthreads();
        // stage h chunk (atomic loads fetch from the coherence point)
        {
            const float* inp = Hin + k * 2048;
#pragma unroll
            for (int u = 0; u < 4; ++u) {
                int e = tid * 4 + u;
                sh.stage[(e >> 7) * 132 + (e & 127)] =
                    atomicAdd((float*)&inp[e], 0.f);
            }
        }
        __syncthreads();
        half8 ahi[4], alo[4];
        const float* arow = &sh.stage[sub * 132];
#pragma unroll
        for (int kc = 0; kc < 4; ++kc) {
            const float4v* p = (const float4v*)(arow + kc * 32 + quad * 8);
            split8v(p[0], p[1], ahi[kc], alo[kc]);
        }
        floatx4 acc[4];
#pragma unroll
        for (int tt = 0; tt < 4; ++tt) {
            floatx4 a = {bias[tt], bias[tt], bias[tt], bias[tt]};
            acc[tt] = a;
        }
#pragma unroll
        for (int tt = 0; tt < 4; ++tt)
#pragma unroll
            for (int kc = 0; kc < 4; ++kc) {
                acc[tt] = __builtin_amdgcn_mfma_f32_16x16x32_f16(ahi[kc], bhi[tt][kc], acc[tt], 0, 0, 0);
                acc[tt] = __builtin_amdgcn_mfma_f32_16x16x32_f16(ahi[kc], blo[tt][kc], acc[tt], 0, 0, 0);
                acc[tt] = __builtin_amdgcn_mfma_f32_16x16x32_f16(alo[kc], bhi[tt][kc], acc[tt], 0, 0, 0);
            }
        // ring WAR: slot k%3 reusable once consumer finished chunk k-3
        if (k >= 3) {
            if (tid == 0) {
                while (atomicAdd(cons, 0) < k - 2) __builtin_amdgcn_s_sleep(16);
            }
            __syncthreads();
        }
        float* dst = PreRing + (k % 3) * 8192;
#pragma unroll
        for (int tt = 0; tt < 4; ++tt)
#pragma unroll
            for (int reg = 0; reg < 4; ++reg)
                dst[(quad * 4 + reg) * 512 + tt * 128 + 16 * w + sub] = acc[tt][reg];
        __syncthreads();               // all stores issued & drained (vmcnt0 at barrier)
        if (tid == 0) {
            __threadfence();           // write back to device coherence point
            atomicExch(&fP[k], 1);
        }
    }
}

// ---------------------------------------------------------------------------
// Rec block (layers 1,2): rec weights resident forever; zero per-chunk
// reloads. Per chunk: flag-acquire (+L1 invalidate) -> 16 r11-verbatim steps
// reading Pre from the ring -> consumed counter; layer1 publishes h.
// ---------------------------------------------------------------------------
__device__ __forceinline__ void rec_body(LstmSh& sh, int b, int layer,
    const float* __restrict__ Whh,
    const float* __restrict__ PreRing, int* __restrict__ fP,
    int* __restrict__ cons,
    float* __restrict__ Hout, int* __restrict__ fHout,  // layer1 only
    float* __restrict__ xl_out)                         // layer2 only
{
    int tid = threadIdx.x;
    int w = tid >> 6, lane = tid & 63, quad = lane >> 4, sub = lane & 15;
    int hu = 16 * w + sub, c4 = quad;
    const float* WhhL = Whh + layer * 65536;

    __builtin_amdgcn_s_setprio(1);
    float4v wgt[4][8];
#pragma unroll
    for (int g = 0; g < 4; ++g) {
        const float4v* p = (const float4v*)(WhhL + (g * 128 + hu) * 128 + c4 * 32);
#pragma unroll
        for (int k = 0; k < 8; ++k) wgt[g][k] = p[k];
    }
    sh.hbuf[0][c4 * 136 + hu] = 0.f;
    float cvar = 0.f;
    __syncthreads();

    for (int k = 0; k < 6; ++k) {
        if (tid == 0) {
            while (atomicAdd(&fP[k], 0) == 0) __builtin_amdgcn_s_sleep(16);
            __threadfence();   // acquire: invalidate this CU's L1 (ring reuse)
        }
        __syncthreads();
        const float* PreC = PreRing + (k % 3) * 8192;
        for (int tl = 0; tl < 16; ++tl) {
            int t = k * 16 + tl;
            int rb = t & 1, wb = rb ^ 1;
            float pre[4];
#pragma unroll
            for (int g = 0; g < 4; ++g)
                pre[g] = PreC[tl * 512 + g * 128 + hu];
            const float4v* hc = (const float4v*)(&sh.hbuf[rb][c4 * 168]);
            float4v p4[4];
#pragma unroll
            for (int g = 0; g < 4; ++g) { float4v z = {0.f,0.f,0.f,0.f}; p4[g] = z; }
#pragma unroll
            for (int kk = 0; kk < 8; ++kk) {
                float4v hv = hc[kk];
#pragma unroll
                for (int g = 0; g < 4; ++g) p4[g] += wgt[g][kk] * hv;
            }
            float p[4];
#pragma unroll
            for (int g = 0; g < 4; ++g) {
                float s = p4[g].x + p4[g].y + p4[g].z + p4[g].w;
                s += __shfl_xor(s, 16, 64);
                s += __shfl_xor(s, 32, 64);
                p[g] = s + pre[g];
            }
            float c = sigm(p[1]) * cvar + sigm(p[0]) * tanhp(p[2]);
            cvar = c;
            float h = sigm(p[3]) * tanhp(c);
            sh.hbuf[wb][c4 * 136 + hu] = h;
            if (c4 == 0) {
                if (layer == 1) sh.stage[tl * 132 + hu] = h;
                else if (t == 95) xl_out[b * 128 + hu] = h;
            }
            __syncthreads();
        }
        if (tid == 0) atomicExch(cons, k + 1);
        if (layer == 1) {
            float* outp = Hout + k * 2048;
#pragma unroll
            for (int u = 0; u < 4; ++u) {
                int e = tid * 4 + u;
                atomicExch(&outp[e], sh.stage[(e >> 7) * 132 + (e & 127)]);
            }
            __syncthreads();
            if (tid == 0) atomicExch(&fHout[k], 1);
        }
    }
    __builtin_amdgcn_s_setprio(0);
}

// ---------------------------------------------------------------------------
// GAT body: r11 VERBATIM.
// ---------------------------------------------------------------------------
__device__ __forceinline__ void gat_body(GatSh& s, int m,
    const float* __restrict__ x, const float* __restrict__ adj,
    const float* __restrict__ W_emb, const float* __restrict__ b_emb,
    const float* __restrict__ W1, const float* __restrict__ a1,
    const float* __restrict__ W2, const float* __restrict__ a2,
    float* __restrict__ attn_out, float* __restrict__ xg)
{
    int tid = threadIdx.x;

    if (tid < 128) s.xv[tid] = x[m * 128 + tid];
#pragma unroll
    for (int base = 0; base < 16384; base += 512) {
        int idx = base + tid;
        unsigned long long msk = __ballot(adj[idx] > 0.f);
        if ((tid & 63) == 0) s.adjm[idx >> 6] = msk;
    }
    if (tid < 32) {
        float su = 0.f, sv = 0.f;
        for (int kk = 0; kk < 32; ++kk) {
            float w1v = W1[kk * 32 + tid];
            su += W_emb[kk] * w1v;
            sv += b_emb[kk] * w1v;
        }
        s.u1[tid] = su; s.v1[tid] = sv;
    }
    __syncthreads();
    if (tid < 4) {
        const float* av = a1 + ((tid >= 2) ? 32 : 0);
        const float* uv = (tid & 1) ? s.v1 : s.u1;
        float sum = 0.f;
        for (int f = 0; f < 32; ++f) sum += uv[f] * av[f];
        s.coef[tid] = sum;
    }
    __syncthreads();
    float cL = s.coef[0], dL = s.coef[1], cR = s.coef[2], dR = s.coef[3];

    {
        int i = tid & 127, q = tid >> 7;
        unsigned int ms = (unsigned int)(s.adjm[(i << 1) | (q >> 1)] >> ((q & 1) * 32));
        float Li = s.xv[i] * cL + dL;
        float den = 0.f, wsum = 0.f;
        int j0 = q * 32;
#pragma unroll
        for (int jj = 0; jj < 32; ++jj) {
            if ((ms >> jj) & 1) {
                float xj = s.xv[j0 + jj];
                float e = Li + xj * cR + dR;
                e = e > 0.f ? e : 0.2f * e;
                float p = fast_exp(e);
                den += p; wsum += p * xj;
            }
        }
        s.d_h[q][i] = den; s.s_h[q][i] = wsum;
    }
    __syncthreads();
    if (tid < 128) {
        float den = 0.f, wsum = 0.f;
#pragma unroll
        for (int q = 0; q < 4; ++q) { den += s.d_h[q][tid]; wsum += s.s_h[q][tid]; }
        s.s1v[tid] = wsum / den;
    }
    __syncthreads();
#pragma unroll
    for (int e0 = 0; e0 < 4096; e0 += 512) {
        int e = e0 + tid;
        int i = e >> 5, f = e & 31;
        float v = s.s1v[i] * s.u1[f] + s.v1[f];
        s.h2s[i * 33 + f] = v > 0.f ? v : fast_exp(v) - 1.f;
    }
    __syncthreads();
    {
        int i = tid >> 2, g0 = (tid & 3) * 4;
        float accv[4] = {0.f, 0.f, 0.f, 0.f};
        for (int f = 0; f < 32; ++f) {
            float hv = s.h2s[i * 33 + f];
#pragma unroll
            for (int g = 0; g < 4; ++g) accv[g] += hv * W2[f * 16 + g0 + g];
        }
#pragma unroll
        for (int g = 0; g < 4; ++g) s.wh2[i * 17 + g0 + g] = accv[g];
    }
    __syncthreads();
    if (tid < 256) {
        int i = tid & 127, which = tid >> 7;
        const float* aa = a2 + which * 16;
        float sum = 0.f;
#pragma unroll
        for (int g = 0; g < 16; ++g) sum += s.wh2[i * 17 + g] * aa[g];
        (which ? s.Rv : s.Lv)[i] = sum;
    }
    __syncthreads();
    {
        int i = tid & 127, q = tid >> 7;
        unsigned int ms = (unsigned int)(s.adjm[(i << 1) | (q >> 1)] >> ((q & 1) * 32));
        float Li = s.Lv[i];
        float den = 0.f;
        int j0 = q * 32;
#pragma unroll
        for (int jj = 0; jj < 32; ++jj) {
            if ((ms >> jj) & 1) {
                float e = Li + s.Rv[j0 + jj];
                e = e > 0.f ? e : 0.2f * e;
                den += fast_exp(e);
            }
        }
        s.d_h[q][i] = den;
    }
    __syncthreads();
    if (tid < 128) {
        float den = 0.f;
#pragma unroll
        for (int q = 0; q < 4; ++q) den += s.d_h[q][tid];
        s.rd2[tid] = 1.0f / den;
    }
    __syncthreads();

    float* aout = attn_out + (size_t)m * 16384;
#pragma unroll
    for (int k = 0; k < 8; ++k) {
        int e0 = k * 2048 + tid * 4;
        int i = e0 >> 7, j0 = e0 & 127;
        unsigned int bits = (unsigned int)(s.adjm[(i << 1) | (j0 >> 6)] >> (j0 & 63)) & 0xFu;
        float Li = s.Lv[i], ri = s.rd2[i];
        float4v p;
#pragma unroll
        for (int u = 0; u < 4; ++u) {
            float pv = 0.f;
            if ((bits >> u) & 1) {
                float e = Li + s.Rv[j0 + u];
                e = e > 0.f ? e : 0.2f * e;
                pv = fast_exp(e) * ri;
            }
            p[u] = pv;
        }
        *(float4v*)(aout + e0) = p;
    }

    if (m % 96 == 95) {
        int b = m / 96;
        int i = tid >> 2, g0 = (tid & 3) * 4;
        unsigned long long mA = s.adjm[i << 1], mB = s.adjm[(i << 1) | 1];
        float Li = s.Lv[i], ri = s.rd2[i];
        float accv[4] = {0.f, 0.f, 0.f, 0.f};
        for (int j = 0; j < 128; ++j) {
            unsigned long long mm = (j < 64) ? mA : mB;
            if ((mm >> (j & 63)) & 1) {
                float e = Li + s.Rv[j];
                e = e > 0.f ? e : 0.2f * e;
                float p = fast_exp(e) * ri;
#pragma unroll
                for (int g = 0; g < 4; ++g) accv[g] += p * s.wh2[j * 17 + g0 + g];
            }
        }
#pragma unroll
        for (int g = 0; g < 4; ++g) xg[b * 2048 + i * 16 + g0 + g] = accv[g];
    }
}

// ---------------------------------------------------------------------------
// Fused kernel. Flag layout per batch (stride 32 ints):
//   [0..5] fH0   [8..13] fP1   [14] cons1
//   [16..21] fH1 [24..29] fP2  [30] cons2
// ---------------------------------------------------------------------------
__global__ __launch_bounds__(512, 2) void fused_kernel(
    const float* __restrict__ x, const float* __restrict__ adj,
    const float* __restrict__ W_emb, const float* __restrict__ b_emb,
    const float* __restrict__ W1, const float* __restrict__ a1,
    const float* __restrict__ W2, const float* __restrict__ a2,
    const float* __restrict__ Wih, const float* __restrict__ Whh,
    const float* __restrict__ bih, const float* __restrict__ bhh,
    float* __restrict__ Pre0, float* __restrict__ Pre1, float* __restrict__ Pre2,
    float* __restrict__ H0, float* __restrict__ H1,
    int* __restrict__ flags, float* __restrict__ xl_out,
    float* __restrict__ attn_out, float* __restrict__ xg)
{
    __shared__ ShU sh;
    int bb = blockIdx.x;
    if (bb < 80) {
        int grp = bb >> 4, b = bb & 15;
        int* F = flags + b * 32;
        if (grp == 0) {
            l0_body(sh.l, b, x, Wih, Whh, bih, bhh,
                    Pre0 + b * 49152, H0 + b * 12288, F + 0);
        } else if (grp == 1) {
            proj_body(sh.l, 1, Wih, bih, bhh,
                      H0 + b * 12288, F + 0, Pre1 + b * 24576, F + 8, F + 14);
        } else if (grp == 2) {
            rec_body(sh.l, b, 1, Whh,
                     Pre1 + b * 24576, F + 8, F + 14,
                     H1 + b * 12288, F + 16, nullptr);
        } else if (grp == 3) {
            proj_body(sh.l, 2, Wih, bih, bhh,
                      H1 + b * 12288, F + 16, Pre2 + b * 24576, F + 24, F + 30);
        } else {
            rec_body(sh.l, b, 2, Whh,
                     Pre2 + b * 24576, F + 24, F + 30,
                     nullptr, nullptr, xl_out);
        }
    } else {
        gat_body(sh.g, bb - 80, x, adj, W_emb, b_emb, W1, a1, W2, a2, attn_out, xg);
    }
}

// ---------------------------------------------------------------------------
// Heads (r11 verbatim)
// ---------------------------------------------------------------------------
__global__ __launch_bounds__(256) void head_partial_kernel(
    const float* __restrict__ xl, const float* __restrict__ xg,
    const float* __restrict__ W1, float* __restrict__ hp)
{
    int k = blockIdx.x >> 4, chunk = blockIdx.x & 15;
    int d = threadIdx.x & 63, bg = threadIdx.x >> 6;
    float acc[4] = {0.f, 0.f, 0.f, 0.f};
    int c0 = chunk * 136;
    for (int cc = c0; cc < c0 + 136; ++cc) {
        float wv = W1[(k * 2176 + cc) * 64 + d];
#pragma unroll
        for (int u = 0; u < 4; ++u) {
            int b = bg * 4 + u;
            float cv = (cc < 128) ? xl[b * 128 + cc] : xg[b * 2048 + cc - 128];
            acc[u] += wv * cv;
        }
    }
#pragma unroll
    for (int u = 0; u < 4; ++u)
        hp[(((k * 16 + chunk) * 16) + bg * 4 + u) * 64 + d] = acc[u];
}

__global__ __launch_bounds__(256) void head_final_kernel(
    const float* __restrict__ hp, const float* __restrict__ b1,
    const float* __restrict__ W2, const float* __restrict__ b2,
    const float* __restrict__ W3d, const float* __restrict__ b3d,
    const float* __restrict__ W3r, const float* __restrict__ b3r,
    const float* __restrict__ W3v, const float* __restrict__ b3v,
    float* __restrict__ out)
{
    __shared__ float h1s[3 * 16 * 64];
    __shared__ float h2s[3 * 16 * 32];
    int tid = threadIdx.x;
    for (int o = tid; o < 3072; o += 256) {
        int k = o >> 10, rem = o & 1023, b = rem >> 6, d = rem & 63;
        float s = b1[k * 64 + d];
        for (int ch = 0; ch < 16; ++ch)
            s += hp[(((k * 16 + ch) * 16) + b) * 64 + d];
        h1s[o] = fmaxf(s, 0.f);
    }
    __syncthreads();
    for (int o = tid; o < 1536; o += 256) {
        int k = o >> 9, rem = o & 511, b = rem >> 5, e = rem & 31;
        float s = b2[k * 32 + e];
        for (int dd = 0; dd < 64; ++dd)
            s += h1s[(k * 16 + b) * 64 + dd] * W2[(k * 64 + dd) * 32 + e];
        h2s[o] = fmaxf(s, 0.f);
    }
    __syncthreads();
    if (tid < 64) {
        if (tid < 16) {
            int b = tid; float s = b3d[0];
            for (int e = 0; e < 32; ++e) s += h2s[b * 32 + e] * W3d[e];
            out[b] = s;
        } else if (tid < 32) {
            int b = tid - 16; float s = b3r[0];
            for (int e = 0; e < 32; ++e) s += h2s[(16 + b) * 32 + e] * W3r[e];
            out[16 + b] = s;
        } else {
            int b = (tid - 32) >> 1, j = tid & 1; float s = b3v[j];
            for (int e = 0; e < 32; ++e) s += h2s[(32 + b) * 32 + e] * W3v[e * 2 + j];
            out[32 + b * 2 + j] = s;
        }
    }
}

// ---------------------------------------------------------------------------
extern "C" void kernel_launch(void* const* d_in, const int* in_sizes, int n_in,
                              void* d_out, int out_size, void* d_ws, size_t ws_size,
                              hipStream_t stream)
{
    const float* x     = (const float*)d_in[0];
    const float* adj   = (const float*)d_in[1];
    const float* W_emb = (const float*)d_in[2];
    const float* b_emb = (const float*)d_in[3];
    const float* W1    = (const float*)d_in[4];
    const float* a1    = (const float*)d_in[5];
    const float* W2    = (const float*)d_in[6];
    const float* a2    = (const float*)d_in[7];
    const float* Wih   = (const float*)d_in[8];
    const float* Whh   = (const float*)d_in[9];
    const float* bih   = (const float*)d_in[10];
    const float* bhh   = (const float*)d_in[11];
    const float* hW1   = (const float*)d_in[12];
    const float* hb1   = (const float*)d_in[13];
    const float* hW2   = (const float*)d_in[14];
    const float* hb2   = (const float*)d_in[15];
    const float* W3d   = (const float*)d_in[16];
    const float* b3d   = (const float*)d_in[17];
    const float* W3r   = (const float*)d_in[18];
    const float* b3r   = (const float*)d_in[19];
    const float* W3v   = (const float*)d_in[20];
    const float* b3v   = (const float*)d_in[21];

    float* out = (float*)d_out;
    float* wsf = (float*)d_ws;
    float* XG    = wsf;                    // 32768
    float* XL    = wsf + 32768;            // 2048
    float* HP    = wsf + 34816;            // 49152 -> 83968
    int*   FLAGS = (int*)(wsf + 83968);    // 16*32 ints (pad to 1024 floats)
    float* PRE0  = wsf + 84992;            // 16*49152 = 786432 -> 871424
    float* PRE1  = wsf + 871424;           // 16*3*8192 = 393216 -> 1264640
    float* PRE2  = wsf + 1264640;          // 393216 -> 1657856
    float* H0    = wsf + 1657856;          // 16*12288 = 196608 -> 1854464
    float* H1    = wsf + 1854464;          // 196608 -> 2051072 (8.2 MB)

    hipMemsetAsync(FLAGS, 0, 16 * 32 * sizeof(int), stream);
    fused_kernel<<<1616, 512, 0, stream>>>(
        x, adj, W_emb, b_emb, W1, a1, W2, a2,
        Wih, Whh, bih, bhh, PRE0, PRE1, PRE2, H0, H1, FLAGS, XL, out + 64, XG);
    head_partial_kernel<<<48, 256, 0, stream>>>(XL, XG, hW1, HP);
    head_final_kernel<<<1, 256, 0, stream>>>(HP, hb1, hW2, hb2, W3d, b3d, W3r, b3r, W3v, b3v, out);
}